// Round 9
// baseline (251.006 us; speedup 1.0000x reference)
//
#include <hip/hip_runtime.h>
#include <math.h>

// LinearAttention B=4, S=2048, D=1024 — bf16 MFMA.
// R9: revert to R7 skeleton (best measured) + three cuts:
//  (1) proj BM=256 ring with k/v column-sums fused into the epilogue
//      (shfl-reduced atomics) -> col-partial pass deleted.
//  (2) out = attnB @ vpT^T split-K x2, fp32 atomicAdd into pre-zeroed out
//      (1024 blocks @3/CU, 32 phases) — halves per-CU phase-slots.
//  (3) R8's Mt/out2 decomposition dropped (phase-slot neutral, proven).
//   proj: BM=256, grid 8x32x3 = 768 blocks (72KB LDS, 2/CU)
//   attn: 256x256 4-phase, grid 8x8x4 = 256 blocks (fp32 + bf16 attnB)
//   out : BM=128 splitK2, grid 8x16x8 = 1024 blocks (48KB LDS, 3/CU)
//
// Workspace map (u16 elems):
//   R0 [0,        8388608): qE  (exp'd q logits -> qp bf16)
//   R1 [8388608, 16777216): kE  (-> kp, normalized in place)
//   R2 [16777216,25165824): Wqb@+0, Wkb@+1M, Wvb@+2M (dead after proj)
//   R3 [25165824,33554432): qb (dead after proj) -> vpT [4,1024,2048]
//   R4 [33554432,50331648): kb@+0, vb@+8.4M (dead after proj) -> attnB bf16
//   tail @ 50331648 (floats): kcolsum[4][1024], vcolsum[4][1024] (@+4096),
//                             kinv(@+131072), vinv(@+135168), biasCat(@+139264)
//   vE lives in d_out's attn region (dead before attn GEMM overwrites it).

typedef float  f32x4  __attribute__((ext_vector_type(4)));
typedef __bf16 bf16x8 __attribute__((ext_vector_type(8)));
typedef int    i32x4  __attribute__((ext_vector_type(4)));
typedef unsigned short u16;

__device__ __forceinline__ float b2f(u16 u) {
    unsigned int i = ((unsigned int)u) << 16; float f;
    __builtin_memcpy(&f, &i, 4); return f;
}
__device__ __forceinline__ u16 f2b(float f) {  // round-to-nearest-even
    unsigned int i; __builtin_memcpy(&i, &f, 4);
    i += 0x7FFFu + ((i >> 16) & 1u);
    return (u16)(i >> 16);
}

// ---- mega convert: q,k,v,Wq,Wk,Wv fp32->bf16 + bias gather -----------------
__global__ __launch_bounds__(256) void cvt_all(
    const float4* __restrict__ q, const float4* __restrict__ k,
    const float4* __restrict__ v, const float4* __restrict__ Wq,
    const float4* __restrict__ Wk, const float4* __restrict__ Wv,
    const float* __restrict__ bq, const float* __restrict__ bk,
    const float* __restrict__ bv,
    ushort4* __restrict__ qb, ushort4* __restrict__ kb,
    ushort4* __restrict__ vb, ushort4* __restrict__ Wb,
    float* __restrict__ biasCat)
{
    int bid = blockIdx.x, t = threadIdx.x;
    const float4* s; ushort4* d; int idx;
    if (bid < 8192)       { s = q;  d = qb;            idx = bid * 256 + t; }
    else if (bid < 16384) { s = k;  d = kb;            idx = (bid - 8192) * 256 + t; }
    else if (bid < 24576) { s = v;  d = vb;            idx = (bid - 16384) * 256 + t; }
    else if (bid < 25600) { s = Wq; d = Wb;            idx = (bid - 24576) * 256 + t; }
    else if (bid < 26624) { s = Wk; d = Wb + 262144;   idx = (bid - 25600) * 256 + t; }
    else if (bid < 27648) { s = Wv; d = Wb + 524288;   idx = (bid - 26624) * 256 + t; }
    else {
        for (int i = t; i < 3072; i += 256)
            biasCat[i] = (i < 1024) ? bq[i] : (i < 2048) ? bk[i - 1024] : bv[i - 2048];
        return;
    }
    float4 vv = s[idx];
    ushort4 o;
    o.x = f2b(vv.x); o.y = f2b(vv.y); o.z = f2b(vv.z); o.w = f2b(vv.w);
    d[idx] = o;
}

// ===========================================================================
// 256x256 4-phase TN GEMM (attn). fp32 direct + bf16 attnB via LDS two-pass.
// ===========================================================================
__global__ __launch_bounds__(512, 2) void gemm256_attn(
    const u16* __restrict__ Ap, const u16* __restrict__ Bp,
    float* __restrict__ C32, u16* __restrict__ C16,
    int N, int K, long long sA, long long sB, long long sC)
{
    __shared__ __align__(16) u16 lds[65536];   // 128 KiB

    const int tid  = threadIdx.x;
    const int lane = tid & 63;
    const int w    = tid >> 6;
    const int wr   = w >> 2, wc = w & 3;

    const int gx  = gridDim.x;
    const int tot = gx * gridDim.y;
    const int lin = blockIdx.y * gx + blockIdx.x;
    const int vlin = (lin & 7) * (tot >> 3) + (lin >> 3);
    const int bx = vlin % gx, by = vlin / gx;
    const int m0 = by * 256, n0 = bx * 256;
    const int z  = blockIdx.z;

    const u16* Ag = Ap + (size_t)z * sA;
    const u16* Bg = Bp + (size_t)z * sB;

    const int cl = tid ^ ((tid >> 4) & 6);
    const int lr = cl >> 3;
    const int ce = (cl & 7) * 8;
    const int arow = m0 + lr;
    const int brow = n0 + (lr & 31) + ((lr & 32) << 1);

    const int axr = ((lane >> 2) & 3) << 4;
    const int ar0 = (wr * 64 + (lane & 15)) * 64 + (lane >> 4) * 8;
    const int br0 = (wc * 32 + (lane & 15)) * 64 + (lane >> 4) * 8;

#define GLL16(gsrc, ldsoff)                                                    \
    __builtin_amdgcn_global_load_lds(                                          \
        (__attribute__((address_space(1))) void*)(uintptr_t)(gsrc),            \
        (__attribute__((address_space(3))) void*)&lds[ldsoff], 16, 0, 0)

#define STAGE_A(c, h, T)                                                       \
    do { const u16* _s = Ag + (size_t)(arow + (h) * 64) * K + (T) * 64 + ce;   \
         int _d = (((c) << 1) + (h)) * 8192 + tid * 8;                         \
         GLL16(_s, _d); GLL16(_s + (size_t)128 * K, _d + 4096); } while (0)

#define STAGE_B(c, g, T)                                                       \
    do { const u16* _s = Bg + (size_t)(brow + (g) * 32) * K + (T) * 64 + ce;   \
         int _d = 32768 + (((c) << 1) + (g)) * 8192 + tid * 8;                 \
         GLL16(_s, _d); GLL16(_s + (size_t)128 * K, _d + 4096); } while (0)

#define SBAR asm volatile("s_barrier" ::: "memory")
#define LGKM0 do { asm volatile("s_waitcnt lgkmcnt(0)" ::: "memory");          \
                   __builtin_amdgcn_sched_barrier(0); } while (0)

#define LDA(base)                                                              \
    _Pragma("unroll") for (int mi2 = 0; mi2 < 4; ++mi2)                        \
    _Pragma("unroll") for (int ks = 0; ks < 2; ++ks)                           \
        afr[mi2][ks] = __builtin_bit_cast(bf16x8,                              \
            *(const i32x4*)&lds[(base) + ((ar0 + mi2 * 1024 + ks * 32) ^ axr)]);

#define LDB(dst, base)                                                         \
    _Pragma("unroll") for (int ni2 = 0; ni2 < 2; ++ni2)                        \
    _Pragma("unroll") for (int ks = 0; ks < 2; ++ks)                           \
        dst[ni2][ks] = __builtin_bit_cast(bf16x8,                              \
            *(const i32x4*)&lds[(base) + ((br0 + ni2 * 1024 + ks * 32) ^ axr)]);

#define MFMA_Q(mb, nb, bfrag)                                                  \
    __builtin_amdgcn_s_setprio(1);                                             \
    _Pragma("unroll") for (int mi2 = 0; mi2 < 4; ++mi2)                        \
    _Pragma("unroll") for (int ni2 = 0; ni2 < 2; ++ni2)                        \
    _Pragma("unroll") for (int ks = 0; ks < 2; ++ks)                           \
        acc[(mb) + mi2][(nb) + ni2] = __builtin_amdgcn_mfma_f32_16x16x32_bf16( \
            afr[mi2][ks], bfrag[ni2][ks], acc[(mb) + mi2][(nb) + ni2], 0, 0, 0); \
    __builtin_amdgcn_s_setprio(0)

    f32x4 acc[8][4];
#pragma unroll
    for (int i = 0; i < 8; ++i)
#pragma unroll
        for (int j = 0; j < 4; ++j) acc[i][j] = (f32x4)0.0f;

    bf16x8 afr[4][2], b0f[2][2], b1f[2][2];

    const int nt = K >> 6;

    STAGE_A(0, 0, 0); STAGE_B(0, 0, 0);
    STAGE_A(0, 1, 0); STAGE_B(0, 1, 0);
    STAGE_A(1, 0, 1); STAGE_B(1, 0, 1);

    for (int T = 0; T < nt; ++T) {
        const int cur = T & 1, nxt = cur ^ 1;
        const int ab = (cur << 1) * 8192;
        const int bb = 32768 + (cur << 1) * 8192;

        if (T + 1 < nt) asm volatile("s_waitcnt vmcnt(4)" ::: "memory");
        else            asm volatile("s_waitcnt vmcnt(0)" ::: "memory");
        SBAR;
        LDA(ab); LDB(b0f, bb);
        if (T + 1 < nt) STAGE_B(nxt, 1, T + 1);
        SBAR; LGKM0;
        MFMA_Q(0, 0, b0f);
        SBAR;
        LDB(b1f, bb + 8192);
        if (T + 1 < nt) STAGE_A(nxt, 1, T + 1);
        SBAR; LGKM0;
        MFMA_Q(0, 2, b1f);
        SBAR;
        LDA(ab + 8192);
        if (T + 2 < nt) STAGE_A(cur, 0, T + 2);
        SBAR; LGKM0;
        MFMA_Q(4, 0, b0f);
        SBAR;
        if (T + 2 < nt) STAGE_B(cur, 0, T + 2);
        SBAR; LGKM0;
        MFMA_Q(4, 2, b1f);
        SBAR;
    }

    // epilogue: fp32 direct + bf16 via LDS two-pass
    const int cr0 = m0 + wr * 128 + ((lane >> 4) << 2);
    const int cc0 = n0 + wc * 64 + (lane & 15);
    float* Cg = C32 + (size_t)z * sC;
#pragma unroll
    for (int mi = 0; mi < 8; ++mi)
#pragma unroll
        for (int ni = 0; ni < 4; ++ni)
#pragma unroll
            for (int j = 0; j < 4; ++j)
                Cg[(size_t)(cr0 + mi * 16 + j) * N + cc0 + ni * 16] = acc[mi][ni][j];

    u16* sE = lds;                         // [128][264] u16
    u16* Cb = C16 + (size_t)z * sC;
    const int wrow0 = ((lane >> 4) << 2);
    const int wcol0 = wc * 64 + (lane & 15);
    const int rr = tid >> 2;
    const int c0 = (tid & 3) * 8;
    __syncthreads();
#pragma unroll
    for (int p = 0; p < 2; ++p) {
        if (wr == p) {
#pragma unroll
            for (int mi = 0; mi < 8; ++mi)
#pragma unroll
                for (int ni = 0; ni < 4; ++ni)
#pragma unroll
                    for (int j = 0; j < 4; ++j)
                        sE[(wrow0 + mi * 16 + j) * 264 + wcol0 + ni * 16] =
                            f2b(acc[mi][ni][j]);
        }
        __syncthreads();
#pragma unroll
        for (int i = 0; i < 8; ++i) {
            i32x4 vv = *(const i32x4*)&sE[rr * 264 + c0 + i * 32];
            *(i32x4*)&Cb[(size_t)(m0 + p * 128 + rr) * N + n0 + c0 + i * 32] = vv;
        }
        if (p == 0) __syncthreads();
    }
#undef GLL16
#undef STAGE_A
#undef STAGE_B
#undef SBAR
#undef LGKM0
#undef LDA
#undef LDB
#undef MFMA_Q
}

// ===========================================================================
// gemm_bw: BMx128 TN GEMM, 256 threads / 4 waves (2M x 2N), per-wave
// (BM/2)x64, BK=32, 3-buffer LDS ring, one phase per K-tile, counted vmcnt.
// KSPLIT: blockIdx.z = z*... zz&3 = batch, zz>>2 = K-chunk (EPI=2 only).
// Swizzle ([*][32] tiles): stage granule cl = g^((g>>3)&3); read elem XOR
// exr = ((lane>>1)&3)<<3.
//  vmcnt: G = BM/64+2 GLLs/stage; boundary leaves stage(T+1) in flight.
//  Ring safety: stage(T+2) targets buf[(T-1)%3], last read retired at
//  lgkm0(T-1) before this phase's barrier. K ascending 32-chunks.
// EPI 1 (proj): exp(acc+bias)->bf16 LDS-coalesced; z==2 -> Calt; fused
//   column sums: z==1 -> csum[b], z==2 -> csum[b]+4096 (atomicAdd of the
//   bf16-ROUNDED values, shfl_xor(16,32)-reduced, lanes<16 only).
// EPI 2 (out, KSPLIT=2): fp32 atomicAdd into pre-zeroed C32 (2 contributors
//   per element -> commutative, bitwise-deterministic).
// ===========================================================================
template<int EPI, int BM, int KSPLIT>
__global__ __launch_bounds__(256, BM == 128 ? 3 : 2) void gemm_bw(
    const u16* __restrict__ Ap, const u16* __restrict__ Bp,
    float* __restrict__ C32, u16* __restrict__ C16, u16* __restrict__ Calt,
    const float* __restrict__ bias, float* __restrict__ csum,
    int N, int K, long long sA, long long sB, long long sC)
{
    constexpr int AMI = BM / 32;            // A frags / acc rows (8 or 4)
    constexpr int ALD = BM / 64;            // A GLLs per stage (4 or 2)
    constexpr int ASZ = BM * 32;            // A buffer elems
    constexpr int BUF = ASZ + 4096;         // ring stride elems
    __shared__ __align__(16) u16 lds[3 * BUF];

    const int tid  = threadIdx.x;
    const int lane = tid & 63;
    const int w    = tid >> 6;
    const int wr   = w >> 1, wc = w & 1;    // 2M x 2N waves

    const int gx  = gridDim.x;
    const int tot = gx * gridDim.y;
    const int lin = blockIdx.y * gx + blockIdx.x;
    const int vlin = (lin & 7) * (tot >> 3) + (lin >> 3);
    const int bx = vlin % gx, by = vlin / gx;
    const int m0 = by * BM, n0 = bx * 128;
    const int zz = blockIdx.z;
    const int z  = (KSPLIT == 1) ? zz : (zz & 3);
    const int kc = (KSPLIT == 1) ? 0 : (zz >> 2);
    const int Kc = K / KSPLIT;              // per-chunk K

    const u16* Ag = Ap + (size_t)z * sA + (size_t)kc * Kc;
    const u16* Bg = Bp + (size_t)z * sB + (size_t)kc * Kc;

    // staging: granule g = ld*256 + tid; cl = g ^ ((g>>3)&3) = ld*256 + cltid
    const int cltid = tid ^ ((tid >> 3) & 3);
    const int crow  = cltid >> 2;           // row within 64-row chunk
    const int ce    = (cltid & 3) * 8;      // col element 0/8/16/24

    // frag reads
    const int exr = ((lane >> 1) & 3) << 3;
    const int ar0 = (wr * (BM / 2) + (lane & 15)) * 32 + (lane >> 4) * 8;
    const int br0 = (wc * 64 + (lane & 15)) * 32 + (lane >> 4) * 8;

#define GLLW(gsrc, ldsoff)                                                     \
    __builtin_amdgcn_global_load_lds(                                          \
        (__attribute__((address_space(1))) void*)(uintptr_t)(gsrc),            \
        (__attribute__((address_space(3))) void*)&lds[ldsoff], 16, 0, 0)

#define STAGE(buf, T)                                                          \
    do {                                                                       \
        _Pragma("unroll") for (int ld = 0; ld < ALD; ++ld)                     \
            GLLW(Ag + (size_t)(m0 + ld * 64 + crow) * K + (T) * 32 + ce,       \
                 (buf) + ld * 2048 + tid * 8);                                 \
        _Pragma("unroll") for (int ld = 0; ld < 2; ++ld)                       \
            GLLW(Bg + (size_t)(n0 + ld * 64 + crow) * K + (T) * 32 + ce,       \
                 (buf) + ASZ + ld * 2048 + tid * 8);                           \
    } while (0)

#define LGKM0B do { asm volatile("s_waitcnt lgkmcnt(0)" ::: "memory");         \
                    __builtin_amdgcn_sched_barrier(0); } while (0)

    f32x4 acc[AMI][4];
#pragma unroll
    for (int i = 0; i < AMI; ++i)
#pragma unroll
        for (int j = 0; j < 4; ++j) acc[i][j] = (f32x4)0.0f;

    bf16x8 afr[AMI], bfr[4];

    const int nt = Kc >> 5;

    int b0 = 0, b1 = BUF, b2 = 2 * BUF;
    STAGE(b0, 0); STAGE(b1, 1);

    for (int T = 0; T < nt; ++T) {
        if (T + 1 < nt) {
            if constexpr (BM == 256) asm volatile("s_waitcnt vmcnt(6)" ::: "memory");
            else                     asm volatile("s_waitcnt vmcnt(4)" ::: "memory");
        } else {
            asm volatile("s_waitcnt vmcnt(0)" ::: "memory");
        }
        asm volatile("s_barrier" ::: "memory");
#pragma unroll
        for (int mi = 0; mi < AMI; ++mi)
            afr[mi] = __builtin_bit_cast(bf16x8,
                *(const i32x4*)&lds[b0 + ((ar0 + mi * 512) ^ exr)]);
#pragma unroll
        for (int ni = 0; ni < 4; ++ni)
            bfr[ni] = __builtin_bit_cast(bf16x8,
                *(const i32x4*)&lds[b0 + ASZ + ((br0 + ni * 512) ^ exr)]);
        if (T + 2 < nt) STAGE(b2, T + 2);
        LGKM0B;
        __builtin_amdgcn_s_setprio(1);
#pragma unroll
        for (int mi = 0; mi < AMI; ++mi)
#pragma unroll
            for (int ni = 0; ni < 4; ++ni)
                acc[mi][ni] = __builtin_amdgcn_mfma_f32_16x16x32_bf16(
                    afr[mi], bfr[ni], acc[mi][ni], 0, 0, 0);
        __builtin_amdgcn_s_setprio(0);
        int tmp = b0; b0 = b1; b1 = b2; b2 = tmp;
    }

    // ---- epilogue ----
    // C row = m0 + wr*(BM/2) + mi*16 + (lane>>4)*4 + j
    // C col = n0 + wc*64 + ni*16 + (lane&15)
    if constexpr (EPI == 1) {                  // proj: exp+bias -> bf16 + colsums
        u16* sE = lds;                         // [BM][136] u16 (69.6KB <= 73.7KB)
        u16* Cb = (z == 2) ? Calt : (C16 + (size_t)z * sC);
        const int colb = wc * 64 + (lane & 15);
        float bv[4], cs[4];
#pragma unroll
        for (int ni = 0; ni < 4; ++ni) {
            bv[ni] = bias[(size_t)z * 1024 + n0 + colb + ni * 16];
            cs[ni] = 0.0f;
        }
        const int wrow0 = wr * (BM / 2) + ((lane >> 4) << 2);
        __syncthreads();                       // loop drained: vmcnt(0)+lgkm0
#pragma unroll
        for (int mi = 0; mi < AMI; ++mi)
#pragma unroll
            for (int ni = 0; ni < 4; ++ni)
#pragma unroll
                for (int j = 0; j < 4; ++j) {
                    u16 h = f2b(__expf(acc[mi][ni][j] + bv[ni]));
                    sE[(wrow0 + mi * 16 + j) * 136 + colb + ni * 16] = h;
                    cs[ni] += b2f(h);          // sum of ROUNDED values
                }
        // fused column sums for k (z==1) and v (z==2)
        if (z >= 1) {
            float* dst = csum + (z - 1) * 4096 + (m0 >> 11) * 1024;
#pragma unroll
            for (int ni = 0; ni < 4; ++ni) {
                float s = cs[ni];
                s += __shfl_xor(s, 16);
                s += __shfl_xor(s, 32);
                if (lane < 16) atomicAdd(&dst[n0 + colb + ni * 16], s);
            }
        }
        __syncthreads();
        const int rr = tid >> 2, c0 = (tid & 3) * 8;
#pragma unroll
        for (int rb = 0; rb < BM / 64; ++rb) {
            int row = rb * 64 + rr;
#pragma unroll
            for (int i = 0; i < 4; ++i) {
                i32x4 vv = *(const i32x4*)&sE[row * 136 + c0 + i * 32];
                *(i32x4*)&Cb[(size_t)(m0 + row) * N + n0 + c0 + i * 32] = vv;
            }
        }
    } else {                                   // out: fp32 atomic accumulate
        float* Cg = C32 + (size_t)z * sC;
        const int cr0 = m0 + wr * (BM / 2) + ((lane >> 4) << 2);
        const int cc0 = n0 + wc * 64 + (lane & 15);
#pragma unroll
        for (int mi = 0; mi < AMI; ++mi)
#pragma unroll
            for (int ni = 0; ni < 4; ++ni)
#pragma unroll
                for (int j = 0; j < 4; ++j) {
                    size_t idx = (size_t)(cr0 + mi * 16 + j) * N + cc0 + ni * 16;
                    if constexpr (KSPLIT == 1) Cg[idx] = acc[mi][ni][j];
                    else                       atomicAdd(&Cg[idx], acc[mi][ni][j]);
                }
    }
#undef GLLW
#undef STAGE
#undef LGKM0B
}

// ---- qE row softmax only (col partials now fused into proj) ----------------
__global__ __launch_bounds__(256) void q_softmax(u16* __restrict__ qE)
{
    size_t row = blockIdx.x;
    u16* p = qE + row * 1024;
    int t = threadIdx.x;
    ushort4 v = *(ushort4*)&p[t * 4];
    float e0 = b2f(v.x), e1 = b2f(v.y), e2 = b2f(v.z), e3 = b2f(v.w);
    float s = (e0 + e1) + (e2 + e3);
#pragma unroll
    for (int off = 32; off; off >>= 1) s += __shfl_down(s, off);
    __shared__ float red[4];
    if ((t & 63) == 0) red[t >> 6] = s;
    __syncthreads();
    float inv = 1.0f / ((red[0] + red[1]) + (red[2] + red[3]));
    ushort4 o;
    o.x = f2b(e0 * inv); o.y = f2b(e1 * inv);
    o.z = f2b(e2 * inv); o.w = f2b(e3 * inv);
    *(ushort4*)&p[t * 4] = o;
}

// ---- colsums -> kinv, vinv -------------------------------------------------
__global__ __launch_bounds__(256) void col_inv(
    const float* __restrict__ csum, float* __restrict__ kinv,
    float* __restrict__ vinv)
{
    int idx = blockIdx.x * 256 + threadIdx.x;  // 0..4095 over (b,e)
    kinv[idx] = 0.03125f / csum[idx];          // 1/sqrt(1024) folded
    vinv[idx] = 1.0f / csum[4096 + idx];
}

// ---- kp in-place col-norm + vp normalize+transpose -------------------------
__global__ __launch_bounds__(256) void norm_all(
    u16* __restrict__ kE, const float* __restrict__ kinv,
    const u16* __restrict__ vE, const float* __restrict__ vinv,
    u16* __restrict__ vpT)
{
    int bid = blockIdx.x, t = threadIdx.x;
    if (bid < 8192) {                          // col_norm on kE
        int b = bid >> 11, s = bid & 2047;
        u16* p = kE + ((size_t)b * 2048 + s) * 1024 + t * 4;
        float4 iv = *(const float4*)(kinv + b * 1024 + t * 4);
        ushort4 v = *(ushort4*)p;
        v.x = f2b(b2f(v.x) * iv.x); v.y = f2b(b2f(v.y) * iv.y);
        v.z = f2b(b2f(v.z) * iv.z); v.w = f2b(b2f(v.w) * iv.w);
        *(ushort4*)p = v;
    } else {                                   // transpose+norm vE -> vpT
        __shared__ __align__(16) u16 tile[64][68];
        int j = bid - 8192;
        int b = j >> 9, y = (j >> 5) & 15, x = j & 31;
        int s0 = x * 64, e0 = y * 64;
        int lr = t >> 4, lc = (t & 15) * 4;
#pragma unroll
        for (int i = 0; i < 4; ++i) {
            int sr = i * 16 + lr;
            ushort4 v = *(const ushort4*)(vE + ((size_t)b * 2048 + s0 + sr) * 1024 + e0 + lc);
            tile[sr][lc] = v.x; tile[sr][lc + 1] = v.y;
            tile[sr][lc + 2] = v.z; tile[sr][lc + 3] = v.w;
        }
        __syncthreads();
#pragma unroll
        for (int i = 0; i < 4; ++i) {
            int er = i * 16 + lr;
            float iv = vinv[b * 1024 + e0 + er];
            ushort4 v;
            v.x = f2b(b2f(tile[lc + 0][er]) * iv);
            v.y = f2b(b2f(tile[lc + 1][er]) * iv);
            v.z = f2b(b2f(tile[lc + 2][er]) * iv);
            v.w = f2b(b2f(tile[lc + 3][er]) * iv);
            *(ushort4*)(vpT + ((size_t)b * 1024 + e0 + er) * 2048 + s0 + lc) = v;
        }
    }
}

extern "C" void kernel_launch(void* const* d_in, const int* in_sizes, int n_in,
                              void* d_out, int out_size, void* d_ws, size_t ws_size,
                              hipStream_t stream)
{
    const float* q  = (const float*)d_in[0];
    const float* k  = (const float*)d_in[1];
    const float* v  = (const float*)d_in[2];
    const float* Wq = (const float*)d_in[3];
    const float* bq = (const float*)d_in[4];
    const float* Wk = (const float*)d_in[5];
    const float* bk = (const float*)d_in[6];
    const float* Wv = (const float*)d_in[7];
    const float* bv = (const float*)d_in[8];

    float* out  = (float*)d_out;          // [4,2048,1024] fp32
    float* attn = out + 8388608;          // [4,2048,2048] fp32

    u16* wsU = (u16*)d_ws;
    u16* qE   = wsU;                      // R0: exp'd q logits -> qp
    u16* kE   = wsU + 8388608;            // R1: exp'd k logits -> kp
    u16* Wb   = wsU + 16777216;           // R2: Wqb|Wkb|Wvb (stride 1M)
    u16* qb   = wsU + 25165824;           // R3: q bf16 (dead after proj)
    u16* kb   = wsU + 33554432;           // R4: k bf16 (dead after proj)
    u16* vb   = wsU + 41943040;           // R4+8.4M: v bf16 (dead after proj)
    u16* vpT  = wsU + 25165824;           // R3 after proj: vpT [4,1024,2048]
    u16* attnB = wsU + 33554432;          // R4 after proj: attn bf16
    u16* vE   = (u16*)attn;               // d_out attn region as scratch

    float* tail  = (float*)(wsU + 50331648);
    float* csum  = tail;                  // kcolsum[4][1024] | vcolsum[4][1024]
    float* kinv  = tail + 131072;         // [4,1024]
    float* vinv  = tail + 135168;
    float* biasCat = tail + 139264;       // [3,1024] bq|bk|bv

    const long long SD = 2048LL * 1024, SS = 2048LL * 2048, DS = 1024LL * 2048;

    // ---- 0: zero out (split-K accumulator) and colsums ----
    hipMemsetAsync(out, 0, 8388608 * sizeof(float), stream);
    hipMemsetAsync(csum, 0, 8192 * sizeof(float), stream);

    // ---- 1: convert inputs + weights to bf16, gather biases ----
    cvt_all<<<dim3(27649), dim3(256), 0, stream>>>(
        (const float4*)q, (const float4*)k, (const float4*)v,
        (const float4*)Wq, (const float4*)Wk, (const float4*)Wv,
        bq, bk, bv,
        (ushort4*)qb, (ushort4*)kb, (ushort4*)vb, (ushort4*)Wb, biasCat);

    // ---- 2: projections (BM=256 ring) + fused k/v colsums ----
    gemm_bw<1, 256, 1><<<dim3(8, 32, 3), dim3(256), 0, stream>>>(
        qb, Wb, nullptr, qE, vE, biasCat, csum,
        1024, 1024, 8388608LL, 1048576LL, 8388608LL);

    // ---- 3: qE row softmax ----
    q_softmax<<<dim3(8192), dim3(256), 0, stream>>>(qE);

    // ---- 4: kinv (x 1/32), vinv from fused colsums ----
    col_inv<<<dim3(16), dim3(256), 0, stream>>>(csum, kinv, vinv);

    // ---- 5: kp col-norm in place + vp normalize+transpose -> vpT ----
    norm_all<<<dim3(10240), dim3(256), 0, stream>>>(kE, kinv, vE, vinv, vpT);

    // ---- 6: attn = qp @ kp^T -> fp32 d_out + bf16 attnB ----
    gemm256_attn<<<dim3(8, 8, 4), dim3(512), 0, stream>>>(
        qE, kE, attn, attnB, 2048, 1024, SD, SD, SS);

    // ---- 7: out = attnB @ vpT^T, split-K x2, fp32 atomic accumulate ----
    gemm_bw<2, 128, 2><<<dim3(8, 16, 8), dim3(256), 0, stream>>>(
        attnB, vpT, out, nullptr, nullptr, nullptr, nullptr,
        1024, 2048, SS, DS, SD);
}

// Round 10
// 210.631 us; speedup vs baseline: 1.1917x; 1.1917x over previous
//
#include <hip/hip_runtime.h>
#include <math.h>

// LinearAttention B=4, S=2048, D=1024 — bf16 MFMA.
// R10: revert to R7 skeleton (best measured, 215.7) + normalization folding:
//  attn = (qp*kinv) @ kE^T   — kinv folded into the qE row-softmax pass;
//                               the kE column-norm pass is DELETED (-33.5MB).
//  out  = vinv[d] * (attnB @ vET^T) — vinv folded into the out epilogue;
//                               vET is a PLAIN transpose of raw vE.
// R9 lessons kept: no split-K atomics (WRITE 2x, MfmaUtil 17%), no memsets.
//   proj: gemm_bw BM=256 ring, grid 8x32x3 = 768 blocks (72KB LDS, 2/CU)
//   attn: 256x256 4-phase, grid 8x8x4 = 256 blocks (fp32 + bf16 attnB)
//   out : gemm_bw BM=128 ring, grid 8x16x4 = 512 blocks (48KB LDS, 3/CU)
//
// Workspace map (u16 elems):
//   R0 [0,        8388608): qE  (exp'd q logits -> qp*kinv bf16)
//   R1 [8388608, 16777216): kE  (raw exp'd k logits — consumed raw by attn)
//   R2 [16777216,25165824): Wqb@+0, Wkb@+1M, Wvb@+2M (dead after proj)
//   R3 [25165824,33554432): qb (dead after proj) -> vET [4,1024,2048]
//   R4 [33554432,50331648): kb@+0, vb@+8.4M (dead after proj) -> attnB bf16
//   tail @ 50331648 (floats): kpart[4,16,1024], vpart(@+65536),
//                             kinv(@+131072), vinv(@+135168), biasCat(@+139264)
//   vE lives in d_out's attn region (dead before attn GEMM overwrites it).

typedef float  f32x4  __attribute__((ext_vector_type(4)));
typedef __bf16 bf16x8 __attribute__((ext_vector_type(8)));
typedef int    i32x4  __attribute__((ext_vector_type(4)));
typedef unsigned short u16;

__device__ __forceinline__ float b2f(u16 u) {
    unsigned int i = ((unsigned int)u) << 16; float f;
    __builtin_memcpy(&f, &i, 4); return f;
}
__device__ __forceinline__ u16 f2b(float f) {  // round-to-nearest-even
    unsigned int i; __builtin_memcpy(&i, &f, 4);
    i += 0x7FFFu + ((i >> 16) & 1u);
    return (u16)(i >> 16);
}

// ---- mega convert: q,k,v,Wq,Wk,Wv fp32->bf16 + bias gather -----------------
__global__ __launch_bounds__(256) void cvt_all(
    const float4* __restrict__ q, const float4* __restrict__ k,
    const float4* __restrict__ v, const float4* __restrict__ Wq,
    const float4* __restrict__ Wk, const float4* __restrict__ Wv,
    const float* __restrict__ bq, const float* __restrict__ bk,
    const float* __restrict__ bv,
    ushort4* __restrict__ qb, ushort4* __restrict__ kb,
    ushort4* __restrict__ vb, ushort4* __restrict__ Wb,
    float* __restrict__ biasCat)
{
    int bid = blockIdx.x, t = threadIdx.x;
    const float4* s; ushort4* d; int idx;
    if (bid < 8192)       { s = q;  d = qb;            idx = bid * 256 + t; }
    else if (bid < 16384) { s = k;  d = kb;            idx = (bid - 8192) * 256 + t; }
    else if (bid < 24576) { s = v;  d = vb;            idx = (bid - 16384) * 256 + t; }
    else if (bid < 25600) { s = Wq; d = Wb;            idx = (bid - 24576) * 256 + t; }
    else if (bid < 26624) { s = Wk; d = Wb + 262144;   idx = (bid - 25600) * 256 + t; }
    else if (bid < 27648) { s = Wv; d = Wb + 524288;   idx = (bid - 26624) * 256 + t; }
    else {
        for (int i = t; i < 3072; i += 256)
            biasCat[i] = (i < 1024) ? bq[i] : (i < 2048) ? bk[i - 1024] : bv[i - 2048];
        return;
    }
    float4 vv = s[idx];
    ushort4 o;
    o.x = f2b(vv.x); o.y = f2b(vv.y); o.z = f2b(vv.z); o.w = f2b(vv.w);
    d[idx] = o;
}

// ===========================================================================
// 256x256 4-phase TN GEMM (attn). fp32 direct + bf16 attnB via LDS two-pass.
// A = qE (kinv-folded), B = RAW kE.
// ===========================================================================
__global__ __launch_bounds__(512, 2) void gemm256_attn(
    const u16* __restrict__ Ap, const u16* __restrict__ Bp,
    float* __restrict__ C32, u16* __restrict__ C16,
    int N, int K, long long sA, long long sB, long long sC)
{
    __shared__ __align__(16) u16 lds[65536];   // 128 KiB

    const int tid  = threadIdx.x;
    const int lane = tid & 63;
    const int w    = tid >> 6;
    const int wr   = w >> 2, wc = w & 3;

    const int gx  = gridDim.x;
    const int tot = gx * gridDim.y;
    const int lin = blockIdx.y * gx + blockIdx.x;
    const int vlin = (lin & 7) * (tot >> 3) + (lin >> 3);
    const int bx = vlin % gx, by = vlin / gx;
    const int m0 = by * 256, n0 = bx * 256;
    const int z  = blockIdx.z;

    const u16* Ag = Ap + (size_t)z * sA;
    const u16* Bg = Bp + (size_t)z * sB;

    const int cl = tid ^ ((tid >> 4) & 6);
    const int lr = cl >> 3;
    const int ce = (cl & 7) * 8;
    const int arow = m0 + lr;
    const int brow = n0 + (lr & 31) + ((lr & 32) << 1);

    const int axr = ((lane >> 2) & 3) << 4;
    const int ar0 = (wr * 64 + (lane & 15)) * 64 + (lane >> 4) * 8;
    const int br0 = (wc * 32 + (lane & 15)) * 64 + (lane >> 4) * 8;

#define GLL16(gsrc, ldsoff)                                                    \
    __builtin_amdgcn_global_load_lds(                                          \
        (__attribute__((address_space(1))) void*)(uintptr_t)(gsrc),            \
        (__attribute__((address_space(3))) void*)&lds[ldsoff], 16, 0, 0)

#define STAGE_A(c, h, T)                                                       \
    do { const u16* _s = Ag + (size_t)(arow + (h) * 64) * K + (T) * 64 + ce;   \
         int _d = (((c) << 1) + (h)) * 8192 + tid * 8;                         \
         GLL16(_s, _d); GLL16(_s + (size_t)128 * K, _d + 4096); } while (0)

#define STAGE_B(c, g, T)                                                       \
    do { const u16* _s = Bg + (size_t)(brow + (g) * 32) * K + (T) * 64 + ce;   \
         int _d = 32768 + (((c) << 1) + (g)) * 8192 + tid * 8;                 \
         GLL16(_s, _d); GLL16(_s + (size_t)128 * K, _d + 4096); } while (0)

#define SBAR asm volatile("s_barrier" ::: "memory")
#define LGKM0 do { asm volatile("s_waitcnt lgkmcnt(0)" ::: "memory");          \
                   __builtin_amdgcn_sched_barrier(0); } while (0)

#define LDA(base)                                                              \
    _Pragma("unroll") for (int mi2 = 0; mi2 < 4; ++mi2)                        \
    _Pragma("unroll") for (int ks = 0; ks < 2; ++ks)                           \
        afr[mi2][ks] = __builtin_bit_cast(bf16x8,                              \
            *(const i32x4*)&lds[(base) + ((ar0 + mi2 * 1024 + ks * 32) ^ axr)]);

#define LDB(dst, base)                                                         \
    _Pragma("unroll") for (int ni2 = 0; ni2 < 2; ++ni2)                        \
    _Pragma("unroll") for (int ks = 0; ks < 2; ++ks)                           \
        dst[ni2][ks] = __builtin_bit_cast(bf16x8,                              \
            *(const i32x4*)&lds[(base) + ((br0 + ni2 * 1024 + ks * 32) ^ axr)]);

#define MFMA_Q(mb, nb, bfrag)                                                  \
    __builtin_amdgcn_s_setprio(1);                                             \
    _Pragma("unroll") for (int mi2 = 0; mi2 < 4; ++mi2)                        \
    _Pragma("unroll") for (int ni2 = 0; ni2 < 2; ++ni2)                        \
    _Pragma("unroll") for (int ks = 0; ks < 2; ++ks)                           \
        acc[(mb) + mi2][(nb) + ni2] = __builtin_amdgcn_mfma_f32_16x16x32_bf16( \
            afr[mi2][ks], bfrag[ni2][ks], acc[(mb) + mi2][(nb) + ni2], 0, 0, 0); \
    __builtin_amdgcn_s_setprio(0)

    f32x4 acc[8][4];
#pragma unroll
    for (int i = 0; i < 8; ++i)
#pragma unroll
        for (int j = 0; j < 4; ++j) acc[i][j] = (f32x4)0.0f;

    bf16x8 afr[4][2], b0f[2][2], b1f[2][2];

    const int nt = K >> 6;

    STAGE_A(0, 0, 0); STAGE_B(0, 0, 0);
    STAGE_A(0, 1, 0); STAGE_B(0, 1, 0);
    STAGE_A(1, 0, 1); STAGE_B(1, 0, 1);

    for (int T = 0; T < nt; ++T) {
        const int cur = T & 1, nxt = cur ^ 1;
        const int ab = (cur << 1) * 8192;
        const int bb = 32768 + (cur << 1) * 8192;

        if (T + 1 < nt) asm volatile("s_waitcnt vmcnt(4)" ::: "memory");
        else            asm volatile("s_waitcnt vmcnt(0)" ::: "memory");
        SBAR;
        LDA(ab); LDB(b0f, bb);
        if (T + 1 < nt) STAGE_B(nxt, 1, T + 1);
        SBAR; LGKM0;
        MFMA_Q(0, 0, b0f);
        SBAR;
        LDB(b1f, bb + 8192);
        if (T + 1 < nt) STAGE_A(nxt, 1, T + 1);
        SBAR; LGKM0;
        MFMA_Q(0, 2, b1f);
        SBAR;
        LDA(ab + 8192);
        if (T + 2 < nt) STAGE_A(cur, 0, T + 2);
        SBAR; LGKM0;
        MFMA_Q(4, 0, b0f);
        SBAR;
        if (T + 2 < nt) STAGE_B(cur, 0, T + 2);
        SBAR; LGKM0;
        MFMA_Q(4, 2, b1f);
        SBAR;
    }

    // epilogue: fp32 direct + bf16 via LDS two-pass
    const int cr0 = m0 + wr * 128 + ((lane >> 4) << 2);
    const int cc0 = n0 + wc * 64 + (lane & 15);
    float* Cg = C32 + (size_t)z * sC;
#pragma unroll
    for (int mi = 0; mi < 8; ++mi)
#pragma unroll
        for (int ni = 0; ni < 4; ++ni)
#pragma unroll
            for (int j = 0; j < 4; ++j)
                Cg[(size_t)(cr0 + mi * 16 + j) * N + cc0 + ni * 16] = acc[mi][ni][j];

    u16* sE = lds;                         // [128][264] u16
    u16* Cb = C16 + (size_t)z * sC;
    const int wrow0 = ((lane >> 4) << 2);
    const int wcol0 = wc * 64 + (lane & 15);
    const int rr = tid >> 2;
    const int c0 = (tid & 3) * 8;
    __syncthreads();
#pragma unroll
    for (int p = 0; p < 2; ++p) {
        if (wr == p) {
#pragma unroll
            for (int mi = 0; mi < 8; ++mi)
#pragma unroll
                for (int ni = 0; ni < 4; ++ni)
#pragma unroll
                    for (int j = 0; j < 4; ++j)
                        sE[(wrow0 + mi * 16 + j) * 264 + wcol0 + ni * 16] =
                            f2b(acc[mi][ni][j]);
        }
        __syncthreads();
#pragma unroll
        for (int i = 0; i < 8; ++i) {
            i32x4 vv = *(const i32x4*)&sE[rr * 264 + c0 + i * 32];
            *(i32x4*)&Cb[(size_t)(m0 + p * 128 + rr) * N + n0 + c0 + i * 32] = vv;
        }
        if (p == 0) __syncthreads();
    }
#undef GLL16
#undef STAGE_A
#undef STAGE_B
#undef SBAR
#undef LGKM0
#undef LDA
#undef LDB
#undef MFMA_Q
}

// ===========================================================================
// gemm_bw: BMx128 TN GEMM, 256 threads / 4 waves (2M x 2N), per-wave
// (BM/2)x64, BK=32, 3-buffer LDS ring, one phase per K-tile, counted vmcnt.
// Swizzle ([*][32] tiles): stage granule cl = g^((g>>3)&3); read elem XOR
// exr = ((lane>>1)&3)<<3.
//  vmcnt: G = BM/64+2 GLLs/stage; boundary leaves stage(T+1) in flight.
//  Ring safety: stage(T+2) targets buf[(T-1)%3], last read retired at
//  lgkm0(T-1) before this phase's barrier. K ascending 32-chunks.
// EPI 1 (proj): exp(acc+bias)->bf16 LDS-coalesced; z==2 -> Calt.
// EPI 2 (out): fp32 direct, scaled by vinv[z*1024 + col] (folded vp norm).
// ===========================================================================
template<int EPI, int BM>
__global__ __launch_bounds__(256, BM == 128 ? 3 : 2) void gemm_bw(
    const u16* __restrict__ Ap, const u16* __restrict__ Bp,
    float* __restrict__ C32, u16* __restrict__ C16, u16* __restrict__ Calt,
    const float* __restrict__ bias, const float* __restrict__ vinv,
    int N, int K, long long sA, long long sB, long long sC)
{
    constexpr int AMI = BM / 32;            // A frags / acc rows (8 or 4)
    constexpr int ALD = BM / 64;            // A GLLs per stage (4 or 2)
    constexpr int ASZ = BM * 32;            // A buffer elems
    constexpr int BUF = ASZ + 4096;         // ring stride elems
    __shared__ __align__(16) u16 lds[3 * BUF];

    const int tid  = threadIdx.x;
    const int lane = tid & 63;
    const int w    = tid >> 6;
    const int wr   = w >> 1, wc = w & 1;    // 2M x 2N waves

    const int gx  = gridDim.x;
    const int tot = gx * gridDim.y;
    const int lin = blockIdx.y * gx + blockIdx.x;
    const int vlin = (lin & 7) * (tot >> 3) + (lin >> 3);
    const int bx = vlin % gx, by = vlin / gx;
    const int m0 = by * BM, n0 = bx * 128;
    const int z  = blockIdx.z;

    const u16* Ag = Ap + (size_t)z * sA;
    const u16* Bg = Bp + (size_t)z * sB;

    // staging: granule g = ld*256 + tid; cl = g ^ ((g>>3)&3) = ld*256 + cltid
    const int cltid = tid ^ ((tid >> 3) & 3);
    const int crow  = cltid >> 2;           // row within 64-row chunk
    const int ce    = (cltid & 3) * 8;      // col element 0/8/16/24

    // frag reads
    const int exr = ((lane >> 1) & 3) << 3;
    const int ar0 = (wr * (BM / 2) + (lane & 15)) * 32 + (lane >> 4) * 8;
    const int br0 = (wc * 64 + (lane & 15)) * 32 + (lane >> 4) * 8;

#define GLLW(gsrc, ldsoff)                                                     \
    __builtin_amdgcn_global_load_lds(                                          \
        (__attribute__((address_space(1))) void*)(uintptr_t)(gsrc),            \
        (__attribute__((address_space(3))) void*)&lds[ldsoff], 16, 0, 0)

#define STAGE(buf, T)                                                          \
    do {                                                                       \
        _Pragma("unroll") for (int ld = 0; ld < ALD; ++ld)                     \
            GLLW(Ag + (size_t)(m0 + ld * 64 + crow) * K + (T) * 32 + ce,       \
                 (buf) + ld * 2048 + tid * 8);                                 \
        _Pragma("unroll") for (int ld = 0; ld < 2; ++ld)                       \
            GLLW(Bg + (size_t)(n0 + ld * 64 + crow) * K + (T) * 32 + ce,       \
                 (buf) + ASZ + ld * 2048 + tid * 8);                           \
    } while (0)

#define LGKM0B do { asm volatile("s_waitcnt lgkmcnt(0)" ::: "memory");         \
                    __builtin_amdgcn_sched_barrier(0); } while (0)

    f32x4 acc[AMI][4];
#pragma unroll
    for (int i = 0; i < AMI; ++i)
#pragma unroll
        for (int j = 0; j < 4; ++j) acc[i][j] = (f32x4)0.0f;

    bf16x8 afr[AMI], bfr[4];

    const int nt = K >> 5;

    int b0 = 0, b1 = BUF, b2 = 2 * BUF;
    STAGE(b0, 0); STAGE(b1, 1);

    for (int T = 0; T < nt; ++T) {
        if (T + 1 < nt) {
            if constexpr (BM == 256) asm volatile("s_waitcnt vmcnt(6)" ::: "memory");
            else                     asm volatile("s_waitcnt vmcnt(4)" ::: "memory");
        } else {
            asm volatile("s_waitcnt vmcnt(0)" ::: "memory");
        }
        asm volatile("s_barrier" ::: "memory");
#pragma unroll
        for (int mi = 0; mi < AMI; ++mi)
            afr[mi] = __builtin_bit_cast(bf16x8,
                *(const i32x4*)&lds[b0 + ((ar0 + mi * 512) ^ exr)]);
#pragma unroll
        for (int ni = 0; ni < 4; ++ni)
            bfr[ni] = __builtin_bit_cast(bf16x8,
                *(const i32x4*)&lds[b0 + ASZ + ((br0 + ni * 512) ^ exr)]);
        if (T + 2 < nt) STAGE(b2, T + 2);
        LGKM0B;
        __builtin_amdgcn_s_setprio(1);
#pragma unroll
        for (int mi = 0; mi < AMI; ++mi)
#pragma unroll
            for (int ni = 0; ni < 4; ++ni)
                acc[mi][ni] = __builtin_amdgcn_mfma_f32_16x16x32_bf16(
                    afr[mi], bfr[ni], acc[mi][ni], 0, 0, 0);
        __builtin_amdgcn_s_setprio(0);
        int tmp = b0; b0 = b1; b1 = b2; b2 = tmp;
    }

    // ---- epilogue ----
    // C row = m0 + wr*(BM/2) + mi*16 + (lane>>4)*4 + j
    // C col = n0 + wc*64 + ni*16 + (lane&15)
    if constexpr (EPI == 1) {                  // proj: exp+bias -> bf16, coalesced
        u16* sE = lds;                         // [BM][136] u16 (fits 3*BUF)
        u16* Cb = (z == 2) ? Calt : (C16 + (size_t)z * sC);
        const int colb = wc * 64 + (lane & 15);
        float bv[4];
#pragma unroll
        for (int ni = 0; ni < 4; ++ni)
            bv[ni] = bias[(size_t)z * 1024 + n0 + colb + ni * 16];
        const int wrow0 = wr * (BM / 2) + ((lane >> 4) << 2);
        __syncthreads();                       // loop drained: vmcnt(0)+lgkm0
#pragma unroll
        for (int mi = 0; mi < AMI; ++mi)
#pragma unroll
            for (int ni = 0; ni < 4; ++ni)
#pragma unroll
                for (int j = 0; j < 4; ++j)
                    sE[(wrow0 + mi * 16 + j) * 136 + colb + ni * 16] =
                        f2b(__expf(acc[mi][ni][j] + bv[ni]));
        __syncthreads();
        const int rr = tid >> 2, c0 = (tid & 3) * 8;
#pragma unroll
        for (int rb = 0; rb < BM / 64; ++rb) {
            int row = rb * 64 + rr;
#pragma unroll
            for (int i = 0; i < 4; ++i) {
                i32x4 vv = *(const i32x4*)&sE[row * 136 + c0 + i * 32];
                *(i32x4*)&Cb[(size_t)(m0 + row) * N + n0 + c0 + i * 32] = vv;
            }
        }
    } else {                                   // out: fp32 direct, * vinv[col]
        float* Cg = C32 + (size_t)z * sC;
        const int cr0 = m0 + wr * (BM / 2) + ((lane >> 4) << 2);
        const int cc0 = n0 + wc * 64 + (lane & 15);
        float vs[4];
#pragma unroll
        for (int ni = 0; ni < 4; ++ni)
            vs[ni] = vinv[(size_t)z * 1024 + cc0 + ni * 16];
#pragma unroll
        for (int mi = 0; mi < AMI; ++mi)
#pragma unroll
            for (int ni = 0; ni < 4; ++ni)
#pragma unroll
                for (int j = 0; j < 4; ++j)
                    Cg[(size_t)(cr0 + mi * 16 + j) * N + cc0 + ni * 16] =
                        acc[mi][ni][j] * vs[ni];
    }
#undef GLLW
#undef STAGE
#undef LGKM0B
}

// ---- column partials over kE, vE (raw), 128-row chunks ---------------------
__global__ __launch_bounds__(256) void colpart(
    const u16* __restrict__ kE, const u16* __restrict__ vE,
    float* __restrict__ kpart, float* __restrict__ vpart)
{
    int j = blockIdx.x, t = threadIdx.x;
    const u16* d; float* part;
    if (j < 64) { d = kE; part = kpart; } else { d = vE; part = vpart; j -= 64; }
    int b = j >> 4, c = j & 15;
    const u16* base = d + ((size_t)b * 2048 + c * 128) * 1024 + t * 4;
    float a0 = 0, a1 = 0, a2 = 0, a3 = 0;
    for (int s = 0; s < 128; ++s) {
        ushort4 v = *(const ushort4*)(base + (size_t)s * 1024);
        a0 += b2f(v.x); a1 += b2f(v.y); a2 += b2f(v.z); a3 += b2f(v.w);
    }
    *(float4*)(part + ((size_t)(b * 16 + c)) * 1024 + t * 4) = make_float4(a0, a1, a2, a3);
}

// ---- reduce partials -> kinv (x 1/32 folded), vinv -------------------------
__global__ __launch_bounds__(256) void col_reduce2(
    const float* __restrict__ kpart, const float* __restrict__ vpart,
    float* __restrict__ kinv, float* __restrict__ vinv)
{
    int bid = blockIdx.x;
    const float* part; float* inv; float mult;
    if (bid < 16) { part = kpart; inv = kinv; mult = 0.03125f; }
    else          { part = vpart; inv = vinv; mult = 1.0f; bid -= 16; }
    int idx = bid * 256 + threadIdx.x;         // 0..4095 over (b,e)
    int b = idx >> 10, e = idx & 1023;
    float s = 0;
    for (int c = 0; c < 16; ++c) s += part[((size_t)(b * 16 + c)) * 1024 + e];
    inv[idx] = mult / s;
}

// ---- qE row softmax WITH kinv fold: qE = (exp/rowsum) * kinv[b,e] ----------
__global__ __launch_bounds__(256) void qsm_scale(
    u16* __restrict__ qE, const float* __restrict__ kinv)
{
    size_t row = blockIdx.x;
    int b = (int)(row >> 11);
    u16* p = qE + row * 1024;
    int t = threadIdx.x;
    ushort4 v = *(ushort4*)&p[t * 4];
    float e0 = b2f(v.x), e1 = b2f(v.y), e2 = b2f(v.z), e3 = b2f(v.w);
    float s = (e0 + e1) + (e2 + e3);
#pragma unroll
    for (int off = 32; off; off >>= 1) s += __shfl_down(s, off);
    __shared__ float red[4];
    if ((t & 63) == 0) red[t >> 6] = s;
    __syncthreads();
    float inv = 1.0f / ((red[0] + red[1]) + (red[2] + red[3]));
    float4 kv = *(const float4*)(kinv + b * 1024 + t * 4);
    ushort4 o;
    o.x = f2b(e0 * inv * kv.x); o.y = f2b(e1 * inv * kv.y);
    o.z = f2b(e2 * inv * kv.z); o.w = f2b(e3 * inv * kv.w);
    *(ushort4*)&p[t * 4] = o;
}

// ---- plain transpose vE[b][s][e] -> vET[b][e][s] (vinv applied in out) -----
__global__ __launch_bounds__(256) void vtrans(
    const u16* __restrict__ vE, u16* __restrict__ vET)
{
    __shared__ __align__(16) u16 tile[64][68];
    int j = blockIdx.x, t = threadIdx.x;
    int b = j >> 9, y = (j >> 5) & 15, x = j & 31;
    int s0 = x * 64, e0 = y * 64;
    int lr = t >> 4, lc = (t & 15) * 4;
#pragma unroll
    for (int i = 0; i < 4; ++i) {
        int sr = i * 16 + lr;
        ushort4 v = *(const ushort4*)(vE + ((size_t)b * 2048 + s0 + sr) * 1024 + e0 + lc);
        tile[sr][lc] = v.x; tile[sr][lc + 1] = v.y;
        tile[sr][lc + 2] = v.z; tile[sr][lc + 3] = v.w;
    }
    __syncthreads();
#pragma unroll
    for (int i = 0; i < 4; ++i) {
        int er = i * 16 + lr;
        ushort4 v;
        v.x = tile[lc + 0][er]; v.y = tile[lc + 1][er];
        v.z = tile[lc + 2][er]; v.w = tile[lc + 3][er];
        *(ushort4*)(vET + ((size_t)b * 1024 + e0 + er) * 2048 + s0 + lc) = v;
    }
}

extern "C" void kernel_launch(void* const* d_in, const int* in_sizes, int n_in,
                              void* d_out, int out_size, void* d_ws, size_t ws_size,
                              hipStream_t stream)
{
    const float* q  = (const float*)d_in[0];
    const float* k  = (const float*)d_in[1];
    const float* v  = (const float*)d_in[2];
    const float* Wq = (const float*)d_in[3];
    const float* bq = (const float*)d_in[4];
    const float* Wk = (const float*)d_in[5];
    const float* bk = (const float*)d_in[6];
    const float* Wv = (const float*)d_in[7];
    const float* bv = (const float*)d_in[8];

    float* out  = (float*)d_out;          // [4,2048,1024] fp32
    float* attn = out + 8388608;          // [4,2048,2048] fp32

    u16* wsU = (u16*)d_ws;
    u16* qE   = wsU;                      // R0: exp'd q logits -> qp*kinv
    u16* kE   = wsU + 8388608;            // R1: exp'd k logits (stays raw)
    u16* Wb   = wsU + 16777216;           // R2: Wqb|Wkb|Wvb (stride 1M)
    u16* qb   = wsU + 25165824;           // R3: q bf16 (dead after proj)
    u16* kb   = wsU + 33554432;           // R4: k bf16 (dead after proj)
    u16* vb   = wsU + 41943040;           // R4+8.4M: v bf16 (dead after proj)
    u16* vET  = wsU + 25165824;           // R3 after proj: vET [4,1024,2048]
    u16* attnB = wsU + 33554432;          // R4 after proj: attn bf16
    u16* vE   = (u16*)attn;               // d_out attn region as scratch

    float* tail  = (float*)(wsU + 50331648);
    float* kpart = tail;                  // [4,16,1024]
    float* vpart = tail + 65536;
    float* kinv  = tail + 131072;         // [4,1024]
    float* vinv  = tail + 135168;
    float* biasCat = tail + 139264;       // [3,1024] bq|bk|bv

    const long long SD = 2048LL * 1024, SS = 2048LL * 2048, DS = 1024LL * 2048;

    // ---- 1: convert inputs + weights to bf16, gather biases ----
    cvt_all<<<dim3(27649), dim3(256), 0, stream>>>(
        (const float4*)q, (const float4*)k, (const float4*)v,
        (const float4*)Wq, (const float4*)Wk, (const float4*)Wv,
        bq, bk, bv,
        (ushort4*)qb, (ushort4*)kb, (ushort4*)vb, (ushort4*)Wb, biasCat);

    // ---- 2: projections (BM=256 ring): z=0/1/2 -> qE, kE, vE ----
    gemm_bw<1, 256><<<dim3(8, 32, 3), dim3(256), 0, stream>>>(
        qb, Wb, nullptr, qE, vE, biasCat, nullptr,
        1024, 1024, 8388608LL, 1048576LL, 8388608LL);

    // ---- 3: column partials over raw kE, vE ----
    colpart<<<dim3(128), dim3(256), 0, stream>>>(kE, vE, kpart, vpart);

    // ---- 4: kinv (x 1/32), vinv ----
    col_reduce2<<<dim3(32), dim3(256), 0, stream>>>(kpart, vpart, kinv, vinv);

    // ---- 5a: qE row softmax with kinv folded in ----
    qsm_scale<<<dim3(8192), dim3(256), 0, stream>>>(qE, kinv);

    // ---- 5b: plain transpose vE -> vET (must precede attn overwrite) ----
    vtrans<<<dim3(2048), dim3(256), 0, stream>>>(vE, vET);

    // ---- 6: attn = (qp*kinv) @ kE^T -> fp32 d_out + bf16 attnB ----
    gemm256_attn<<<dim3(8, 8, 4), dim3(512), 0, stream>>>(
        qE, kE, attn, attnB, 2048, 1024, SD, SD, SS);

    // ---- 7: out = (attnB @ vET^T) * vinv -> fp32 d_out ----
    gemm_bw<2, 128><<<dim3(8, 16, 4), dim3(256), 0, stream>>>(
        attnB, vET, out, nullptr, nullptr, nullptr, vinv,
        1024, 2048, SS, DS, SD);
}

// Round 11
// 209.263 us; speedup vs baseline: 1.1995x; 1.0065x over previous
//
#include <hip/hip_runtime.h>
#include <math.h>

// LinearAttention B=4, S=2048, D=1024 — bf16 MFMA.
// R11 (single change vs R10, best=210.6): remove the LGKM0 pin
// (lgkmcnt(0)+sched_barrier(0)) before the MFMA blocks in gemm_bw and
// gemm256_attn. The fragment reads are plain C++ LDS loads (NOT inline-asm),
// so the compiler tracks per-register deps and emits fine-grained lgkmcnt —
// the explicit full drain serialized all 12 reads before the first MFMA
// (~1100 of the measured 1650 cyc/phase serial path; MfmaUtil pinned at 32%).
// vmcnt+barrier boundaries (buffer lifetime) unchanged; FP order unchanged.
//   proj: gemm_bw BM=256 ring, grid 8x32x3 = 768 blocks (72KB LDS, 2/CU)
//   attn: 256x256 4-phase, grid 8x8x4 = 256 blocks (fp32 + bf16 attnB)
//   out : gemm_bw BM=128 ring, grid 8x16x4 = 512 blocks (48KB LDS, 3/CU)
//
// Workspace map (u16 elems):
//   R0 [0,        8388608): qE  (exp'd q logits -> qp*kinv bf16)
//   R1 [8388608, 16777216): kE  (raw exp'd k logits — consumed raw by attn)
//   R2 [16777216,25165824): Wqb@+0, Wkb@+1M, Wvb@+2M (dead after proj)
//   R3 [25165824,33554432): qb (dead after proj) -> vET [4,1024,2048]
//   R4 [33554432,50331648): kb@+0, vb@+8.4M (dead after proj) -> attnB bf16
//   tail @ 50331648 (floats): kpart[4,16,1024], vpart(@+65536),
//                             kinv(@+131072), vinv(@+135168), biasCat(@+139264)
//   vE lives in d_out's attn region (dead before attn GEMM overwrites it).

typedef float  f32x4  __attribute__((ext_vector_type(4)));
typedef __bf16 bf16x8 __attribute__((ext_vector_type(8)));
typedef int    i32x4  __attribute__((ext_vector_type(4)));
typedef unsigned short u16;

__device__ __forceinline__ float b2f(u16 u) {
    unsigned int i = ((unsigned int)u) << 16; float f;
    __builtin_memcpy(&f, &i, 4); return f;
}
__device__ __forceinline__ u16 f2b(float f) {  // round-to-nearest-even
    unsigned int i; __builtin_memcpy(&i, &f, 4);
    i += 0x7FFFu + ((i >> 16) & 1u);
    return (u16)(i >> 16);
}

// ---- mega convert: q,k,v,Wq,Wk,Wv fp32->bf16 + bias gather -----------------
__global__ __launch_bounds__(256) void cvt_all(
    const float4* __restrict__ q, const float4* __restrict__ k,
    const float4* __restrict__ v, const float4* __restrict__ Wq,
    const float4* __restrict__ Wk, const float4* __restrict__ Wv,
    const float* __restrict__ bq, const float* __restrict__ bk,
    const float* __restrict__ bv,
    ushort4* __restrict__ qb, ushort4* __restrict__ kb,
    ushort4* __restrict__ vb, ushort4* __restrict__ Wb,
    float* __restrict__ biasCat)
{
    int bid = blockIdx.x, t = threadIdx.x;
    const float4* s; ushort4* d; int idx;
    if (bid < 8192)       { s = q;  d = qb;            idx = bid * 256 + t; }
    else if (bid < 16384) { s = k;  d = kb;            idx = (bid - 8192) * 256 + t; }
    else if (bid < 24576) { s = v;  d = vb;            idx = (bid - 16384) * 256 + t; }
    else if (bid < 25600) { s = Wq; d = Wb;            idx = (bid - 24576) * 256 + t; }
    else if (bid < 26624) { s = Wk; d = Wb + 262144;   idx = (bid - 25600) * 256 + t; }
    else if (bid < 27648) { s = Wv; d = Wb + 524288;   idx = (bid - 26624) * 256 + t; }
    else {
        for (int i = t; i < 3072; i += 256)
            biasCat[i] = (i < 1024) ? bq[i] : (i < 2048) ? bk[i - 1024] : bv[i - 2048];
        return;
    }
    float4 vv = s[idx];
    ushort4 o;
    o.x = f2b(vv.x); o.y = f2b(vv.y); o.z = f2b(vv.z); o.w = f2b(vv.w);
    d[idx] = o;
}

// ===========================================================================
// 256x256 4-phase TN GEMM (attn). fp32 direct + bf16 attnB via LDS two-pass.
// A = qE (kinv-folded), B = RAW kE. R11: no lgkm pin — compiler emits
// fine-grained lgkmcnt per MFMA operand.
// ===========================================================================
__global__ __launch_bounds__(512, 2) void gemm256_attn(
    const u16* __restrict__ Ap, const u16* __restrict__ Bp,
    float* __restrict__ C32, u16* __restrict__ C16,
    int N, int K, long long sA, long long sB, long long sC)
{
    __shared__ __align__(16) u16 lds[65536];   // 128 KiB

    const int tid  = threadIdx.x;
    const int lane = tid & 63;
    const int w    = tid >> 6;
    const int wr   = w >> 2, wc = w & 3;

    const int gx  = gridDim.x;
    const int tot = gx * gridDim.y;
    const int lin = blockIdx.y * gx + blockIdx.x;
    const int vlin = (lin & 7) * (tot >> 3) + (lin >> 3);
    const int bx = vlin % gx, by = vlin / gx;
    const int m0 = by * 256, n0 = bx * 256;
    const int z  = blockIdx.z;

    const u16* Ag = Ap + (size_t)z * sA;
    const u16* Bg = Bp + (size_t)z * sB;

    const int cl = tid ^ ((tid >> 4) & 6);
    const int lr = cl >> 3;
    const int ce = (cl & 7) * 8;
    const int arow = m0 + lr;
    const int brow = n0 + (lr & 31) + ((lr & 32) << 1);

    const int axr = ((lane >> 2) & 3) << 4;
    const int ar0 = (wr * 64 + (lane & 15)) * 64 + (lane >> 4) * 8;
    const int br0 = (wc * 32 + (lane & 15)) * 64 + (lane >> 4) * 8;

#define GLL16(gsrc, ldsoff)                                                    \
    __builtin_amdgcn_global_load_lds(                                          \
        (__attribute__((address_space(1))) void*)(uintptr_t)(gsrc),            \
        (__attribute__((address_space(3))) void*)&lds[ldsoff], 16, 0, 0)

#define STAGE_A(c, h, T)                                                       \
    do { const u16* _s = Ag + (size_t)(arow + (h) * 64) * K + (T) * 64 + ce;   \
         int _d = (((c) << 1) + (h)) * 8192 + tid * 8;                         \
         GLL16(_s, _d); GLL16(_s + (size_t)128 * K, _d + 4096); } while (0)

#define STAGE_B(c, g, T)                                                       \
    do { const u16* _s = Bg + (size_t)(brow + (g) * 32) * K + (T) * 64 + ce;   \
         int _d = 32768 + (((c) << 1) + (g)) * 8192 + tid * 8;                 \
         GLL16(_s, _d); GLL16(_s + (size_t)128 * K, _d + 4096); } while (0)

#define SBAR asm volatile("s_barrier" ::: "memory")

#define LDA(base)                                                              \
    _Pragma("unroll") for (int mi2 = 0; mi2 < 4; ++mi2)                        \
    _Pragma("unroll") for (int ks = 0; ks < 2; ++ks)                           \
        afr[mi2][ks] = __builtin_bit_cast(bf16x8,                              \
            *(const i32x4*)&lds[(base) + ((ar0 + mi2 * 1024 + ks * 32) ^ axr)]);

#define LDB(dst, base)                                                         \
    _Pragma("unroll") for (int ni2 = 0; ni2 < 2; ++ni2)                        \
    _Pragma("unroll") for (int ks = 0; ks < 2; ++ks)                           \
        dst[ni2][ks] = __builtin_bit_cast(bf16x8,                              \
            *(const i32x4*)&lds[(base) + ((br0 + ni2 * 1024 + ks * 32) ^ axr)]);

#define MFMA_Q(mb, nb, bfrag)                                                  \
    __builtin_amdgcn_s_setprio(1);                                             \
    _Pragma("unroll") for (int mi2 = 0; mi2 < 4; ++mi2)                        \
    _Pragma("unroll") for (int ni2 = 0; ni2 < 2; ++ni2)                        \
    _Pragma("unroll") for (int ks = 0; ks < 2; ++ks)                           \
        acc[(mb) + mi2][(nb) + ni2] = __builtin_amdgcn_mfma_f32_16x16x32_bf16( \
            afr[mi2][ks], bfrag[ni2][ks], acc[(mb) + mi2][(nb) + ni2], 0, 0, 0); \
    __builtin_amdgcn_s_setprio(0)

    f32x4 acc[8][4];
#pragma unroll
    for (int i = 0; i < 8; ++i)
#pragma unroll
        for (int j = 0; j < 4; ++j) acc[i][j] = (f32x4)0.0f;

    bf16x8 afr[4][2], b0f[2][2], b1f[2][2];

    const int nt = K >> 6;

    STAGE_A(0, 0, 0); STAGE_B(0, 0, 0);
    STAGE_A(0, 1, 0); STAGE_B(0, 1, 0);
    STAGE_A(1, 0, 1); STAGE_B(1, 0, 1);

    for (int T = 0; T < nt; ++T) {
        const int cur = T & 1, nxt = cur ^ 1;
        const int ab = (cur << 1) * 8192;
        const int bb = 32768 + (cur << 1) * 8192;

        if (T + 1 < nt) asm volatile("s_waitcnt vmcnt(4)" ::: "memory");
        else            asm volatile("s_waitcnt vmcnt(0)" ::: "memory");
        SBAR;
        LDA(ab); LDB(b0f, bb);
        if (T + 1 < nt) STAGE_B(nxt, 1, T + 1);
        SBAR;
        MFMA_Q(0, 0, b0f);
        SBAR;
        LDB(b1f, bb + 8192);
        if (T + 1 < nt) STAGE_A(nxt, 1, T + 1);
        SBAR;
        MFMA_Q(0, 2, b1f);
        SBAR;
        LDA(ab + 8192);
        if (T + 2 < nt) STAGE_A(cur, 0, T + 2);
        SBAR;
        MFMA_Q(4, 0, b0f);
        SBAR;
        if (T + 2 < nt) STAGE_B(cur, 0, T + 2);
        SBAR;
        MFMA_Q(4, 2, b1f);
        SBAR;
    }

    // epilogue: fp32 direct + bf16 via LDS two-pass
    const int cr0 = m0 + wr * 128 + ((lane >> 4) << 2);
    const int cc0 = n0 + wc * 64 + (lane & 15);
    float* Cg = C32 + (size_t)z * sC;
#pragma unroll
    for (int mi = 0; mi < 8; ++mi)
#pragma unroll
        for (int ni = 0; ni < 4; ++ni)
#pragma unroll
            for (int j = 0; j < 4; ++j)
                Cg[(size_t)(cr0 + mi * 16 + j) * N + cc0 + ni * 16] = acc[mi][ni][j];

    u16* sE = lds;                         // [128][264] u16
    u16* Cb = C16 + (size_t)z * sC;
    const int wrow0 = ((lane >> 4) << 2);
    const int wcol0 = wc * 64 + (lane & 15);
    const int rr = tid >> 2;
    const int c0 = (tid & 3) * 8;
    __syncthreads();
#pragma unroll
    for (int p = 0; p < 2; ++p) {
        if (wr == p) {
#pragma unroll
            for (int mi = 0; mi < 8; ++mi)
#pragma unroll
                for (int ni = 0; ni < 4; ++ni)
#pragma unroll
                    for (int j = 0; j < 4; ++j)
                        sE[(wrow0 + mi * 16 + j) * 264 + wcol0 + ni * 16] =
                            f2b(acc[mi][ni][j]);
        }
        __syncthreads();
#pragma unroll
        for (int i = 0; i < 8; ++i) {
            i32x4 vv = *(const i32x4*)&sE[rr * 264 + c0 + i * 32];
            *(i32x4*)&Cb[(size_t)(m0 + p * 128 + rr) * N + n0 + c0 + i * 32] = vv;
        }
        if (p == 0) __syncthreads();
    }
#undef GLL16
#undef STAGE_A
#undef STAGE_B
#undef SBAR
#undef LDA
#undef LDB
#undef MFMA_Q
}

// ===========================================================================
// gemm_bw: BMx128 TN GEMM, 256 threads / 4 waves (2M x 2N), per-wave
// (BM/2)x64, BK=32, 3-buffer LDS ring, one phase per K-tile, counted vmcnt.
// R11: no lgkm pin — plain-load frags, compiler fine-schedules reads into
// the MFMA block (first MFMA starts when its operands land).
// Swizzle ([*][32] tiles): stage granule cl = g^((g>>3)&3); read elem XOR
// exr = ((lane>>1)&3)<<3.
//  vmcnt: G = BM/64+2 GLLs/stage; boundary leaves stage(T+1) in flight.
//  Ring safety: stage(T+2) targets buf[(T-1)%3], last read consumed before
//  that phase's MFMA (reads fenced by the asm barrier at phase entry).
// EPI 1 (proj): exp(acc+bias)->bf16 LDS-coalesced; z==2 -> Calt.
// EPI 2 (out): fp32 direct, scaled by vinv[z*1024 + col] (folded vp norm).
// ===========================================================================
template<int EPI, int BM>
__global__ __launch_bounds__(256, BM == 128 ? 3 : 2) void gemm_bw(
    const u16* __restrict__ Ap, const u16* __restrict__ Bp,
    float* __restrict__ C32, u16* __restrict__ C16, u16* __restrict__ Calt,
    const float* __restrict__ bias, const float* __restrict__ vinv,
    int N, int K, long long sA, long long sB, long long sC)
{
    constexpr int AMI = BM / 32;            // A frags / acc rows (8 or 4)
    constexpr int ALD = BM / 64;            // A GLLs per stage (4 or 2)
    constexpr int ASZ = BM * 32;            // A buffer elems
    constexpr int BUF = ASZ + 4096;         // ring stride elems
    __shared__ __align__(16) u16 lds[3 * BUF];

    const int tid  = threadIdx.x;
    const int lane = tid & 63;
    const int w    = tid >> 6;
    const int wr   = w >> 1, wc = w & 1;    // 2M x 2N waves

    const int gx  = gridDim.x;
    const int tot = gx * gridDim.y;
    const int lin = blockIdx.y * gx + blockIdx.x;
    const int vlin = (lin & 7) * (tot >> 3) + (lin >> 3);
    const int bx = vlin % gx, by = vlin / gx;
    const int m0 = by * BM, n0 = bx * 128;
    const int z  = blockIdx.z;

    const u16* Ag = Ap + (size_t)z * sA;
    const u16* Bg = Bp + (size_t)z * sB;

    // staging: granule g = ld*256 + tid; cl = g ^ ((g>>3)&3) = ld*256 + cltid
    const int cltid = tid ^ ((tid >> 3) & 3);
    const int crow  = cltid >> 2;           // row within 64-row chunk
    const int ce    = (cltid & 3) * 8;      // col element 0/8/16/24

    // frag reads
    const int exr = ((lane >> 1) & 3) << 3;
    const int ar0 = (wr * (BM / 2) + (lane & 15)) * 32 + (lane >> 4) * 8;
    const int br0 = (wc * 64 + (lane & 15)) * 32 + (lane >> 4) * 8;

#define GLLW(gsrc, ldsoff)                                                     \
    __builtin_amdgcn_global_load_lds(                                          \
        (__attribute__((address_space(1))) void*)(uintptr_t)(gsrc),            \
        (__attribute__((address_space(3))) void*)&lds[ldsoff], 16, 0, 0)

#define STAGE(buf, T)                                                          \
    do {                                                                       \
        _Pragma("unroll") for (int ld = 0; ld < ALD; ++ld)                     \
            GLLW(Ag + (size_t)(m0 + ld * 64 + crow) * K + (T) * 32 + ce,       \
                 (buf) + ld * 2048 + tid * 8);                                 \
        _Pragma("unroll") for (int ld = 0; ld < 2; ++ld)                       \
            GLLW(Bg + (size_t)(n0 + ld * 64 + crow) * K + (T) * 32 + ce,       \
                 (buf) + ASZ + ld * 2048 + tid * 8);                           \
    } while (0)

    f32x4 acc[AMI][4];
#pragma unroll
    for (int i = 0; i < AMI; ++i)
#pragma unroll
        for (int j = 0; j < 4; ++j) acc[i][j] = (f32x4)0.0f;

    bf16x8 afr[AMI], bfr[4];

    const int nt = K >> 5;

    int b0 = 0, b1 = BUF, b2 = 2 * BUF;
    STAGE(b0, 0); STAGE(b1, 1);

    for (int T = 0; T < nt; ++T) {
        if (T + 1 < nt) {
            if constexpr (BM == 256) asm volatile("s_waitcnt vmcnt(6)" ::: "memory");
            else                     asm volatile("s_waitcnt vmcnt(4)" ::: "memory");
        } else {
            asm volatile("s_waitcnt vmcnt(0)" ::: "memory");
        }
        asm volatile("s_barrier" ::: "memory");
#pragma unroll
        for (int mi = 0; mi < AMI; ++mi)
            afr[mi] = __builtin_bit_cast(bf16x8,
                *(const i32x4*)&lds[b0 + ((ar0 + mi * 512) ^ exr)]);
#pragma unroll
        for (int ni = 0; ni < 4; ++ni)
            bfr[ni] = __builtin_bit_cast(bf16x8,
                *(const i32x4*)&lds[b0 + ASZ + ((br0 + ni * 512) ^ exr)]);
        if (T + 2 < nt) STAGE(b2, T + 2);
        __builtin_amdgcn_s_setprio(1);
#pragma unroll
        for (int mi = 0; mi < AMI; ++mi)
#pragma unroll
            for (int ni = 0; ni < 4; ++ni)
                acc[mi][ni] = __builtin_amdgcn_mfma_f32_16x16x32_bf16(
                    afr[mi], bfr[ni], acc[mi][ni], 0, 0, 0);
        __builtin_amdgcn_s_setprio(0);
        int tmp = b0; b0 = b1; b1 = b2; b2 = tmp;
    }

    // ---- epilogue ----
    // C row = m0 + wr*(BM/2) + mi*16 + (lane>>4)*4 + j
    // C col = n0 + wc*64 + ni*16 + (lane&15)
    if constexpr (EPI == 1) {                  // proj: exp+bias -> bf16, coalesced
        u16* sE = lds;                         // [BM][136] u16 (fits 3*BUF)
        u16* Cb = (z == 2) ? Calt : (C16 + (size_t)z * sC);
        const int colb = wc * 64 + (lane & 15);
        float bv[4];
#pragma unroll
        for (int ni = 0; ni < 4; ++ni)
            bv[ni] = bias[(size_t)z * 1024 + n0 + colb + ni * 16];
        const int wrow0 = wr * (BM / 2) + ((lane >> 4) << 2);
        __syncthreads();                       // loop drained (vmcnt0 + lgkm)
#pragma unroll
        for (int mi = 0; mi < AMI; ++mi)
#pragma unroll
            for (int ni = 0; ni < 4; ++ni)
#pragma unroll
                for (int j = 0; j < 4; ++j)
                    sE[(wrow0 + mi * 16 + j) * 136 + colb + ni * 16] =
                        f2b(__expf(acc[mi][ni][j] + bv[ni]));
        __syncthreads();
        const int rr = tid >> 2, c0 = (tid & 3) * 8;
#pragma unroll
        for (int rb = 0; rb < BM / 64; ++rb) {
            int row = rb * 64 + rr;
#pragma unroll
            for (int i = 0; i < 4; ++i) {
                i32x4 vv = *(const i32x4*)&sE[row * 136 + c0 + i * 32];
                *(i32x4*)&Cb[(size_t)(m0 + row) * N + n0 + c0 + i * 32] = vv;
            }
        }
    } else {                                   // out: fp32 direct, * vinv[col]
        float* Cg = C32 + (size_t)z * sC;
        const int cr0 = m0 + wr * (BM / 2) + ((lane >> 4) << 2);
        const int cc0 = n0 + wc * 64 + (lane & 15);
        float vs[4];
#pragma unroll
        for (int ni = 0; ni < 4; ++ni)
            vs[ni] = vinv[(size_t)z * 1024 + cc0 + ni * 16];
#pragma unroll
        for (int mi = 0; mi < AMI; ++mi)
#pragma unroll
            for (int ni = 0; ni < 4; ++ni)
#pragma unroll
                for (int j = 0; j < 4; ++j)
                    Cg[(size_t)(cr0 + mi * 16 + j) * N + cc0 + ni * 16] =
                        acc[mi][ni][j] * vs[ni];
    }
#undef GLLW
#undef STAGE
}

// ---- column partials over kE, vE (raw), 128-row chunks ---------------------
__global__ __launch_bounds__(256) void colpart(
    const u16* __restrict__ kE, const u16* __restrict__ vE,
    float* __restrict__ kpart, float* __restrict__ vpart)
{
    int j = blockIdx.x, t = threadIdx.x;
    const u16* d; float* part;
    if (j < 64) { d = kE; part = kpart; } else { d = vE; part = vpart; j -= 64; }
    int b = j >> 4, c = j & 15;
    const u16* base = d + ((size_t)b * 2048 + c * 128) * 1024 + t * 4;
    float a0 = 0, a1 = 0, a2 = 0, a3 = 0;
    for (int s = 0; s < 128; ++s) {
        ushort4 v = *(const ushort4*)(base + (size_t)s * 1024);
        a0 += b2f(v.x); a1 += b2f(v.y); a2 += b2f(v.z); a3 += b2f(v.w);
    }
    *(float4*)(part + ((size_t)(b * 16 + c)) * 1024 + t * 4) = make_float4(a0, a1, a2, a3);
}

// ---- reduce partials -> kinv (x 1/32 folded), vinv -------------------------
__global__ __launch_bounds__(256) void col_reduce2(
    const float* __restrict__ kpart, const float* __restrict__ vpart,
    float* __restrict__ kinv, float* __restrict__ vinv)
{
    int bid = blockIdx.x;
    const float* part; float* inv; float mult;
    if (bid < 16) { part = kpart; inv = kinv; mult = 0.03125f; }
    else          { part = vpart; inv = vinv; mult = 1.0f; bid -= 16; }
    int idx = bid * 256 + threadIdx.x;         // 0..4095 over (b,e)
    int b = idx >> 10, e = idx & 1023;
    float s = 0;
    for (int c = 0; c < 16; ++c) s += part[((size_t)(b * 16 + c)) * 1024 + e];
    inv[idx] = mult / s;
}

// ---- qE row softmax WITH kinv fold: qE = (exp/rowsum) * kinv[b,e] ----------
__global__ __launch_bounds__(256) void qsm_scale(
    u16* __restrict__ qE, const float* __restrict__ kinv)
{
    size_t row = blockIdx.x;
    int b = (int)(row >> 11);
    u16* p = qE + row * 1024;
    int t = threadIdx.x;
    ushort4 v = *(ushort4*)&p[t * 4];
    float e0 = b2f(v.x), e1 = b2f(v.y), e2 = b2f(v.z), e3 = b2f(v.w);
    float s = (e0 + e1) + (e2 + e3);
#pragma unroll
    for (int off = 32; off; off >>= 1) s += __shfl_down(s, off);
    __shared__ float red[4];
    if ((t & 63) == 0) red[t >> 6] = s;
    __syncthreads();
    float inv = 1.0f / ((red[0] + red[1]) + (red[2] + red[3]));
    float4 kv = *(const float4*)(kinv + b * 1024 + t * 4);
    ushort4 o;
    o.x = f2b(e0 * inv * kv.x); o.y = f2b(e1 * inv * kv.y);
    o.z = f2b(e2 * inv * kv.z); o.w = f2b(e3 * inv * kv.w);
    *(ushort4*)&p[t * 4] = o;
}

// ---- plain transpose vE[b][s][e] -> vET[b][e][s] (vinv applied in out) -----
__global__ __launch_bounds__(256) void vtrans(
    const u16* __restrict__ vE, u16* __restrict__ vET)
{
    __shared__ __align__(16) u16 tile[64][68];
    int j = blockIdx.x, t = threadIdx.x;
    int b = j >> 9, y = (j >> 5) & 15, x = j & 31;
    int s0 = x * 64, e0 = y * 64;
    int lr = t >> 4, lc = (t & 15) * 4;
#pragma unroll
    for (int i = 0; i < 4; ++i) {
        int sr = i * 16 + lr;
        ushort4 v = *(const ushort4*)(vE + ((size_t)b * 2048 + s0 + sr) * 1024 + e0 + lc);
        tile[sr][lc] = v.x; tile[sr][lc + 1] = v.y;
        tile[sr][lc + 2] = v.z; tile[sr][lc + 3] = v.w;
    }
    __syncthreads();
#pragma unroll
    for (int i = 0; i < 4; ++i) {
        int er = i * 16 + lr;
        ushort4 v;
        v.x = tile[lc + 0][er]; v.y = tile[lc + 1][er];
        v.z = tile[lc + 2][er]; v.w = tile[lc + 3][er];
        *(ushort4*)(vET + ((size_t)b * 1024 + e0 + er) * 2048 + s0 + lc) = v;
    }
}

extern "C" void kernel_launch(void* const* d_in, const int* in_sizes, int n_in,
                              void* d_out, int out_size, void* d_ws, size_t ws_size,
                              hipStream_t stream)
{
    const float* q  = (const float*)d_in[0];
    const float* k  = (const float*)d_in[1];
    const float* v  = (const float*)d_in[2];
    const float* Wq = (const float*)d_in[3];
    const float* bq = (const float*)d_in[4];
    const float* Wk = (const float*)d_in[5];
    const float* bk = (const float*)d_in[6];
    const float* Wv = (const float*)d_in[7];
    const float* bv = (const float*)d_in[8];

    float* out  = (float*)d_out;          // [4,2048,1024] fp32
    float* attn = out + 8388608;          // [4,2048,2048] fp32

    u16* wsU = (u16*)d_ws;
    u16* qE   = wsU;                      // R0: exp'd q logits -> qp*kinv
    u16* kE   = wsU + 8388608;            // R1: exp'd k logits (stays raw)
    u16* Wb   = wsU + 16777216;           // R2: Wqb|Wkb|Wvb (stride 1M)
    u16* qb   = wsU + 25165824;           // R3: q bf16 (dead after proj)
    u16* kb   = wsU + 33554432;           // R4: k bf16 (dead after proj)
    u16* vb   = wsU + 41943040;           // R4+8.4M: v bf16 (dead after proj)
    u16* vET  = wsU + 25165824;           // R3 after proj: vET [4,1024,2048]
    u16* attnB = wsU + 33554432;          // R4 after proj: attn bf16
    u16* vE   = (u16*)attn;               // d_out attn region as scratch

    float* tail  = (float*)(wsU + 50331648);
    float* kpart = tail;                  // [4,16,1024]
    float* vpart = tail + 65536;
    float* kinv  = tail + 131072;         // [4,1024]
    float* vinv  = tail + 135168;
    float* biasCat = tail + 139264;       // [3,1024] bq|bk|bv

    const long long SD = 2048LL * 1024, SS = 2048LL * 2048, DS = 1024LL * 2048;

    // ---- 1: convert inputs + weights to bf16, gather biases ----
    cvt_all<<<dim3(27649), dim3(256), 0, stream>>>(
        (const float4*)q, (const float4*)k, (const float4*)v,
        (const float4*)Wq, (const float4*)Wk, (const float4*)Wv,
        bq, bk, bv,
        (ushort4*)qb, (ushort4*)kb, (ushort4*)vb, (ushort4*)Wb, biasCat);

    // ---- 2: projections (BM=256 ring): z=0/1/2 -> qE, kE, vE ----
    gemm_bw<1, 256><<<dim3(8, 32, 3), dim3(256), 0, stream>>>(
        qb, Wb, nullptr, qE, vE, biasCat, nullptr,
        1024, 1024, 8388608LL, 1048576LL, 8388608LL);

    // ---- 3: column partials over raw kE, vE ----
    colpart<<<dim3(128), dim3(256), 0, stream>>>(kE, vE, kpart, vpart);

    // ---- 4: kinv (x 1/32), vinv ----
    col_reduce2<<<dim3(32), dim3(256), 0, stream>>>(kpart, vpart, kinv, vinv);

    // ---- 5a: qE row softmax with kinv folded in ----
    qsm_scale<<<dim3(8192), dim3(256), 0, stream>>>(qE, kinv);

    // ---- 5b: plain transpose vE -> vET (must precede attn overwrite) ----
    vtrans<<<dim3(2048), dim3(256), 0, stream>>>(vE, vET);

    // ---- 6: attn = (qp*kinv) @ kE^T -> fp32 d_out + bf16 attnB ----
    gemm256_attn<<<dim3(8, 8, 4), dim3(512), 0, stream>>>(
        qE, kE, attn, attnB, 2048, 1024, SD, SD, SS);

    // ---- 7: out = (attnB @ vET^T) * vinv -> fp32 d_out ----
    gemm_bw<2, 128><<<dim3(8, 16, 4), dim3(256), 0, stream>>>(
        attnB, vET, out, nullptr, nullptr, nullptr, vinv,
        1024, 2048, SS, DS, SD);
}

// Round 12
// 200.182 us; speedup vs baseline: 1.2539x; 1.0454x over previous
//
#include <hip/hip_runtime.h>
#include <math.h>

// LinearAttention B=4, S=2048, D=1024 — bf16 MFMA.
// R12 (base = R11 best 209.3): elementwise-chain fusion, GEMM loops untouched.
//  (1) k/v column sums fused into proj epilogue (shfl_xor reduce + atomics;
//      R9 evidenced absmax-neutral). colpart kernel DELETED.
//  (2) col_reduce2 DELETED — consumers divide inline (identical fp ops:
//      kinv=0.03125f/ksum in qsm; vinv=1.0f/vsum in out epilogue).
//  (3) qsm + vtrans merged into one dispatch. csum zeroed inside cvt_all.
//  Launches 8 -> 5.
//   proj: gemm_bw BM=256 ring, grid 8x32x3 = 768 blocks (72KB LDS, 2/CU)
//   attn: 256x256 4-phase, grid 8x8x4 = 256 blocks (fp32 + bf16 attnB)
//   out : gemm_bw BM=128 ring, grid 8x16x4 = 512 blocks (48KB LDS, 3/CU)
//
// Workspace map (u16 elems):
//   R0 [0,        8388608): qE  (exp'd q logits -> qp*kinv bf16)
//   R1 [8388608, 16777216): kE  (raw exp'd k logits — consumed raw by attn)
//   R2 [16777216,25165824): Wqb@+0, Wkb@+1M, Wvb@+2M (dead after proj)
//   R3 [25165824,33554432): qb (dead after proj) -> vET [4,1024,2048]
//   R4 [33554432,50331648): kb@+0, vb@+8.4M (dead after proj) -> attnB bf16
//   tail @ 50331648 (floats): csum = kcolsum[4][1024] | vcolsum[4][1024],
//                             biasCat[3][1024] @ +139264
//   vE lives in d_out's attn region (dead before attn GEMM overwrites it).

typedef float  f32x4  __attribute__((ext_vector_type(4)));
typedef __bf16 bf16x8 __attribute__((ext_vector_type(8)));
typedef int    i32x4  __attribute__((ext_vector_type(4)));
typedef unsigned short u16;

__device__ __forceinline__ float b2f(u16 u) {
    unsigned int i = ((unsigned int)u) << 16; float f;
    __builtin_memcpy(&f, &i, 4); return f;
}
__device__ __forceinline__ u16 f2b(float f) {  // round-to-nearest-even
    unsigned int i; __builtin_memcpy(&i, &f, 4);
    i += 0x7FFFu + ((i >> 16) & 1u);
    return (u16)(i >> 16);
}

// ---- mega convert: q,k,v,Wq,Wk,Wv fp32->bf16 + bias gather + csum zero -----
__global__ __launch_bounds__(256) void cvt_all(
    const float4* __restrict__ q, const float4* __restrict__ k,
    const float4* __restrict__ v, const float4* __restrict__ Wq,
    const float4* __restrict__ Wk, const float4* __restrict__ Wv,
    const float* __restrict__ bq, const float* __restrict__ bk,
    const float* __restrict__ bv,
    ushort4* __restrict__ qb, ushort4* __restrict__ kb,
    ushort4* __restrict__ vb, ushort4* __restrict__ Wb,
    float* __restrict__ biasCat, float* __restrict__ csum)
{
    int bid = blockIdx.x, t = threadIdx.x;
    const float4* s; ushort4* d; int idx;
    if (bid < 8192)       { s = q;  d = qb;            idx = bid * 256 + t; }
    else if (bid < 16384) { s = k;  d = kb;            idx = (bid - 8192) * 256 + t; }
    else if (bid < 24576) { s = v;  d = vb;            idx = (bid - 16384) * 256 + t; }
    else if (bid < 25600) { s = Wq; d = Wb;            idx = (bid - 24576) * 256 + t; }
    else if (bid < 26624) { s = Wk; d = Wb + 262144;   idx = (bid - 25600) * 256 + t; }
    else if (bid < 27648) { s = Wv; d = Wb + 524288;   idx = (bid - 26624) * 256 + t; }
    else {
        for (int i = t; i < 3072; i += 256)
            biasCat[i] = (i < 1024) ? bq[i] : (i < 2048) ? bk[i - 1024] : bv[i - 2048];
        for (int i = t; i < 8192; i += 256) csum[i] = 0.0f;
        return;
    }
    float4 vv = s[idx];
    ushort4 o;
    o.x = f2b(vv.x); o.y = f2b(vv.y); o.z = f2b(vv.z); o.w = f2b(vv.w);
    d[idx] = o;
}

// ===========================================================================
// 256x256 4-phase TN GEMM (attn). fp32 direct + bf16 attnB via LDS two-pass.
// A = qE (kinv-folded), B = RAW kE.
// ===========================================================================
__global__ __launch_bounds__(512, 2) void gemm256_attn(
    const u16* __restrict__ Ap, const u16* __restrict__ Bp,
    float* __restrict__ C32, u16* __restrict__ C16,
    int N, int K, long long sA, long long sB, long long sC)
{
    __shared__ __align__(16) u16 lds[65536];   // 128 KiB

    const int tid  = threadIdx.x;
    const int lane = tid & 63;
    const int w    = tid >> 6;
    const int wr   = w >> 2, wc = w & 3;

    const int gx  = gridDim.x;
    const int tot = gx * gridDim.y;
    const int lin = blockIdx.y * gx + blockIdx.x;
    const int vlin = (lin & 7) * (tot >> 3) + (lin >> 3);
    const int bx = vlin % gx, by = vlin / gx;
    const int m0 = by * 256, n0 = bx * 256;
    const int z  = blockIdx.z;

    const u16* Ag = Ap + (size_t)z * sA;
    const u16* Bg = Bp + (size_t)z * sB;

    const int cl = tid ^ ((tid >> 4) & 6);
    const int lr = cl >> 3;
    const int ce = (cl & 7) * 8;
    const int arow = m0 + lr;
    const int brow = n0 + (lr & 31) + ((lr & 32) << 1);

    const int axr = ((lane >> 2) & 3) << 4;
    const int ar0 = (wr * 64 + (lane & 15)) * 64 + (lane >> 4) * 8;
    const int br0 = (wc * 32 + (lane & 15)) * 64 + (lane >> 4) * 8;

#define GLL16(gsrc, ldsoff)                                                    \
    __builtin_amdgcn_global_load_lds(                                          \
        (__attribute__((address_space(1))) void*)(uintptr_t)(gsrc),            \
        (__attribute__((address_space(3))) void*)&lds[ldsoff], 16, 0, 0)

#define STAGE_A(c, h, T)                                                       \
    do { const u16* _s = Ag + (size_t)(arow + (h) * 64) * K + (T) * 64 + ce;   \
         int _d = (((c) << 1) + (h)) * 8192 + tid * 8;                         \
         GLL16(_s, _d); GLL16(_s + (size_t)128 * K, _d + 4096); } while (0)

#define STAGE_B(c, g, T)                                                       \
    do { const u16* _s = Bg + (size_t)(brow + (g) * 32) * K + (T) * 64 + ce;   \
         int _d = 32768 + (((c) << 1) + (g)) * 8192 + tid * 8;                 \
         GLL16(_s, _d); GLL16(_s + (size_t)128 * K, _d + 4096); } while (0)

#define SBAR asm volatile("s_barrier" ::: "memory")

#define LDA(base)                                                              \
    _Pragma("unroll") for (int mi2 = 0; mi2 < 4; ++mi2)                        \
    _Pragma("unroll") for (int ks = 0; ks < 2; ++ks)                           \
        afr[mi2][ks] = __builtin_bit_cast(bf16x8,                              \
            *(const i32x4*)&lds[(base) + ((ar0 + mi2 * 1024 + ks * 32) ^ axr)]);

#define LDB(dst, base)                                                         \
    _Pragma("unroll") for (int ni2 = 0; ni2 < 2; ++ni2)                        \
    _Pragma("unroll") for (int ks = 0; ks < 2; ++ks)                           \
        dst[ni2][ks] = __builtin_bit_cast(bf16x8,                              \
            *(const i32x4*)&lds[(base) + ((br0 + ni2 * 1024 + ks * 32) ^ axr)]);

#define MFMA_Q(mb, nb, bfrag)                                                  \
    __builtin_amdgcn_s_setprio(1);                                             \
    _Pragma("unroll") for (int mi2 = 0; mi2 < 4; ++mi2)                        \
    _Pragma("unroll") for (int ni2 = 0; ni2 < 2; ++ni2)                        \
    _Pragma("unroll") for (int ks = 0; ks < 2; ++ks)                           \
        acc[(mb) + mi2][(nb) + ni2] = __builtin_amdgcn_mfma_f32_16x16x32_bf16( \
            afr[mi2][ks], bfrag[ni2][ks], acc[(mb) + mi2][(nb) + ni2], 0, 0, 0); \
    __builtin_amdgcn_s_setprio(0)

    f32x4 acc[8][4];
#pragma unroll
    for (int i = 0; i < 8; ++i)
#pragma unroll
        for (int j = 0; j < 4; ++j) acc[i][j] = (f32x4)0.0f;

    bf16x8 afr[4][2], b0f[2][2], b1f[2][2];

    const int nt = K >> 6;

    STAGE_A(0, 0, 0); STAGE_B(0, 0, 0);
    STAGE_A(0, 1, 0); STAGE_B(0, 1, 0);
    STAGE_A(1, 0, 1); STAGE_B(1, 0, 1);

    for (int T = 0; T < nt; ++T) {
        const int cur = T & 1, nxt = cur ^ 1;
        const int ab = (cur << 1) * 8192;
        const int bb = 32768 + (cur << 1) * 8192;

        if (T + 1 < nt) asm volatile("s_waitcnt vmcnt(4)" ::: "memory");
        else            asm volatile("s_waitcnt vmcnt(0)" ::: "memory");
        SBAR;
        LDA(ab); LDB(b0f, bb);
        if (T + 1 < nt) STAGE_B(nxt, 1, T + 1);
        SBAR;
        MFMA_Q(0, 0, b0f);
        SBAR;
        LDB(b1f, bb + 8192);
        if (T + 1 < nt) STAGE_A(nxt, 1, T + 1);
        SBAR;
        MFMA_Q(0, 2, b1f);
        SBAR;
        LDA(ab + 8192);
        if (T + 2 < nt) STAGE_A(cur, 0, T + 2);
        SBAR;
        MFMA_Q(4, 0, b0f);
        SBAR;
        if (T + 2 < nt) STAGE_B(cur, 0, T + 2);
        SBAR;
        MFMA_Q(4, 2, b1f);
        SBAR;
    }

    // epilogue: fp32 direct + bf16 via LDS two-pass
    const int cr0 = m0 + wr * 128 + ((lane >> 4) << 2);
    const int cc0 = n0 + wc * 64 + (lane & 15);
    float* Cg = C32 + (size_t)z * sC;
#pragma unroll
    for (int mi = 0; mi < 8; ++mi)
#pragma unroll
        for (int ni = 0; ni < 4; ++ni)
#pragma unroll
            for (int j = 0; j < 4; ++j)
                Cg[(size_t)(cr0 + mi * 16 + j) * N + cc0 + ni * 16] = acc[mi][ni][j];

    u16* sE = lds;                         // [128][264] u16
    u16* Cb = C16 + (size_t)z * sC;
    const int wrow0 = ((lane >> 4) << 2);
    const int wcol0 = wc * 64 + (lane & 15);
    const int rr = tid >> 2;
    const int c0 = (tid & 3) * 8;
    __syncthreads();
#pragma unroll
    for (int p = 0; p < 2; ++p) {
        if (wr == p) {
#pragma unroll
            for (int mi = 0; mi < 8; ++mi)
#pragma unroll
                for (int ni = 0; ni < 4; ++ni)
#pragma unroll
                    for (int j = 0; j < 4; ++j)
                        sE[(wrow0 + mi * 16 + j) * 264 + wcol0 + ni * 16] =
                            f2b(acc[mi][ni][j]);
        }
        __syncthreads();
#pragma unroll
        for (int i = 0; i < 8; ++i) {
            i32x4 vv = *(const i32x4*)&sE[rr * 264 + c0 + i * 32];
            *(i32x4*)&Cb[(size_t)(m0 + p * 128 + rr) * N + n0 + c0 + i * 32] = vv;
        }
        if (p == 0) __syncthreads();
    }
#undef GLL16
#undef STAGE_A
#undef STAGE_B
#undef SBAR
#undef LDA
#undef LDB
#undef MFMA_Q
}

// ===========================================================================
// gemm_bw: BMx128 TN GEMM, 256 threads / 4 waves (2M x 2N), per-wave
// (BM/2)x64, BK=32, 3-buffer LDS ring, one phase per K-tile, counted vmcnt.
// Swizzle ([*][32] tiles): stage granule cl = g^((g>>3)&3); read elem XOR
// exr = ((lane>>1)&3)<<3.
//  vmcnt: G = BM/64+2 GLLs/stage; boundary leaves stage(T+1) in flight.
//  Ring safety: stage(T+2) targets buf[(T-1)%3], last read consumed before
//  that phase's MFMA (reads fenced by the asm barrier at phase entry).
// EPI 1 (proj): exp(acc+bias)->bf16 LDS-coalesced; z==2 -> Calt; FUSED
//   column sums for k (z==1) / v (z==2): per-thread partials over rounded
//   values, shfl_xor(16,32) wave reduce, lanes<16 atomicAdd into aux
//   (= csum; k at +0, v at +4096; per-batch segment (m0>>11)*1024).
// EPI 2 (out): fp32 direct, scaled by 1/aux[z*1024+col] (aux = vcolsum).
// ===========================================================================
template<int EPI, int BM>
__global__ __launch_bounds__(256, BM == 128 ? 3 : 2) void gemm_bw(
    const u16* __restrict__ Ap, const u16* __restrict__ Bp,
    float* __restrict__ C32, u16* __restrict__ C16, u16* __restrict__ Calt,
    const float* __restrict__ bias, float* __restrict__ aux,
    int N, int K, long long sA, long long sB, long long sC)
{
    constexpr int AMI = BM / 32;            // A frags / acc rows (8 or 4)
    constexpr int ALD = BM / 64;            // A GLLs per stage (4 or 2)
    constexpr int ASZ = BM * 32;            // A buffer elems
    constexpr int BUF = ASZ + 4096;         // ring stride elems
    __shared__ __align__(16) u16 lds[3 * BUF];

    const int tid  = threadIdx.x;
    const int lane = tid & 63;
    const int w    = tid >> 6;
    const int wr   = w >> 1, wc = w & 1;    // 2M x 2N waves

    const int gx  = gridDim.x;
    const int tot = gx * gridDim.y;
    const int lin = blockIdx.y * gx + blockIdx.x;
    const int vlin = (lin & 7) * (tot >> 3) + (lin >> 3);
    const int bx = vlin % gx, by = vlin / gx;
    const int m0 = by * BM, n0 = bx * 128;
    const int z  = blockIdx.z;

    const u16* Ag = Ap + (size_t)z * sA;
    const u16* Bg = Bp + (size_t)z * sB;

    // staging: granule g = ld*256 + tid; cl = g ^ ((g>>3)&3) = ld*256 + cltid
    const int cltid = tid ^ ((tid >> 3) & 3);
    const int crow  = cltid >> 2;           // row within 64-row chunk
    const int ce    = (cltid & 3) * 8;      // col element 0/8/16/24

    // frag reads
    const int exr = ((lane >> 1) & 3) << 3;
    const int ar0 = (wr * (BM / 2) + (lane & 15)) * 32 + (lane >> 4) * 8;
    const int br0 = (wc * 64 + (lane & 15)) * 32 + (lane >> 4) * 8;

#define GLLW(gsrc, ldsoff)                                                     \
    __builtin_amdgcn_global_load_lds(                                          \
        (__attribute__((address_space(1))) void*)(uintptr_t)(gsrc),            \
        (__attribute__((address_space(3))) void*)&lds[ldsoff], 16, 0, 0)

#define STAGE(buf, T)                                                          \
    do {                                                                       \
        _Pragma("unroll") for (int ld = 0; ld < ALD; ++ld)                     \
            GLLW(Ag + (size_t)(m0 + ld * 64 + crow) * K + (T) * 32 + ce,       \
                 (buf) + ld * 2048 + tid * 8);                                 \
        _Pragma("unroll") for (int ld = 0; ld < 2; ++ld)                       \
            GLLW(Bg + (size_t)(n0 + ld * 64 + crow) * K + (T) * 32 + ce,       \
                 (buf) + ASZ + ld * 2048 + tid * 8);                           \
    } while (0)

    f32x4 acc[AMI][4];
#pragma unroll
    for (int i = 0; i < AMI; ++i)
#pragma unroll
        for (int j = 0; j < 4; ++j) acc[i][j] = (f32x4)0.0f;

    bf16x8 afr[AMI], bfr[4];

    const int nt = K >> 5;

    int b0 = 0, b1 = BUF, b2 = 2 * BUF;
    STAGE(b0, 0); STAGE(b1, 1);

    for (int T = 0; T < nt; ++T) {
        if (T + 1 < nt) {
            if constexpr (BM == 256) asm volatile("s_waitcnt vmcnt(6)" ::: "memory");
            else                     asm volatile("s_waitcnt vmcnt(4)" ::: "memory");
        } else {
            asm volatile("s_waitcnt vmcnt(0)" ::: "memory");
        }
        asm volatile("s_barrier" ::: "memory");
#pragma unroll
        for (int mi = 0; mi < AMI; ++mi)
            afr[mi] = __builtin_bit_cast(bf16x8,
                *(const i32x4*)&lds[b0 + ((ar0 + mi * 512) ^ exr)]);
#pragma unroll
        for (int ni = 0; ni < 4; ++ni)
            bfr[ni] = __builtin_bit_cast(bf16x8,
                *(const i32x4*)&lds[b0 + ASZ + ((br0 + ni * 512) ^ exr)]);
        if (T + 2 < nt) STAGE(b2, T + 2);
        __builtin_amdgcn_s_setprio(1);
#pragma unroll
        for (int mi = 0; mi < AMI; ++mi)
#pragma unroll
            for (int ni = 0; ni < 4; ++ni)
                acc[mi][ni] = __builtin_amdgcn_mfma_f32_16x16x32_bf16(
                    afr[mi], bfr[ni], acc[mi][ni], 0, 0, 0);
        __builtin_amdgcn_s_setprio(0);
        int tmp = b0; b0 = b1; b1 = b2; b2 = tmp;
    }

    // ---- epilogue ----
    // C row = m0 + wr*(BM/2) + mi*16 + (lane>>4)*4 + j
    // C col = n0 + wc*64 + ni*16 + (lane&15)
    if constexpr (EPI == 1) {                  // proj: exp+bias -> bf16 + colsums
        u16* sE = lds;                         // [BM][136] u16 (fits 3*BUF)
        u16* Cb = (z == 2) ? Calt : (C16 + (size_t)z * sC);
        const int colb = wc * 64 + (lane & 15);
        float bv[4], cs[4];
#pragma unroll
        for (int ni = 0; ni < 4; ++ni) {
            bv[ni] = bias[(size_t)z * 1024 + n0 + colb + ni * 16];
            cs[ni] = 0.0f;
        }
        const int wrow0 = wr * (BM / 2) + ((lane >> 4) << 2);
        __syncthreads();                       // loop drained (vmcnt0 + lgkm)
#pragma unroll
        for (int mi = 0; mi < AMI; ++mi)
#pragma unroll
            for (int ni = 0; ni < 4; ++ni)
#pragma unroll
                for (int j = 0; j < 4; ++j) {
                    u16 h = f2b(__expf(acc[mi][ni][j] + bv[ni]));
                    sE[(wrow0 + mi * 16 + j) * 136 + colb + ni * 16] = h;
                    cs[ni] += b2f(h);          // sum of ROUNDED values
                }
        if (z >= 1) {                          // fused colsums: k->+0, v->+4096
            float* dst = aux + (z - 1) * 4096 + (m0 >> 11) * 1024;
#pragma unroll
            for (int ni = 0; ni < 4; ++ni) {
                float s = cs[ni];
                s += __shfl_xor(s, 16);
                s += __shfl_xor(s, 32);
                if (lane < 16) atomicAdd(&dst[n0 + colb + ni * 16], s);
            }
        }
        __syncthreads();
        const int rr = tid >> 2, c0 = (tid & 3) * 8;
#pragma unroll
        for (int rb = 0; rb < BM / 64; ++rb) {
            int row = rb * 64 + rr;
#pragma unroll
            for (int i = 0; i < 4; ++i) {
                i32x4 vv = *(const i32x4*)&sE[row * 136 + c0 + i * 32];
                *(i32x4*)&Cb[(size_t)(m0 + row) * N + n0 + c0 + i * 32] = vv;
            }
        }
    } else {                                   // out: fp32 direct, * 1/vsum[col]
        float* Cg = C32 + (size_t)z * sC;
        const int cr0 = m0 + wr * (BM / 2) + ((lane >> 4) << 2);
        const int cc0 = n0 + wc * 64 + (lane & 15);
        float vs[4];
#pragma unroll
        for (int ni = 0; ni < 4; ++ni)
            vs[ni] = 1.0f / aux[(size_t)z * 1024 + cc0 + ni * 16];
#pragma unroll
        for (int mi = 0; mi < AMI; ++mi)
#pragma unroll
            for (int ni = 0; ni < 4; ++ni)
#pragma unroll
                for (int j = 0; j < 4; ++j)
                    Cg[(size_t)(cr0 + mi * 16 + j) * N + cc0 + ni * 16] =
                        acc[mi][ni][j] * vs[ni];
    }
#undef GLLW
#undef STAGE
}

// ---- fused: qE row softmax (kinv inline) + plain transpose vE -> vET -------
__global__ __launch_bounds__(256) void qsm_vtrans(
    u16* __restrict__ qE, const float* __restrict__ csum,
    const u16* __restrict__ vE, u16* __restrict__ vET)
{
    __shared__ __align__(16) u16 tile[64][68];
    __shared__ float red[4];
    int bid = blockIdx.x, t = threadIdx.x;
    if (bid < 8192) {                          // qE = (exp/rowsum)*(c/ksum)
        int b = bid >> 11;
        u16* p = qE + (size_t)bid * 1024;
        ushort4 v = *(ushort4*)&p[t * 4];
        float e0 = b2f(v.x), e1 = b2f(v.y), e2 = b2f(v.z), e3 = b2f(v.w);
        float s = (e0 + e1) + (e2 + e3);
#pragma unroll
        for (int off = 32; off; off >>= 1) s += __shfl_down(s, off);
        if ((t & 63) == 0) red[t >> 6] = s;
        __syncthreads();
        float inv = 1.0f / ((red[0] + red[1]) + (red[2] + red[3]));
        float4 ks = *(const float4*)(csum + b * 1024 + t * 4);
        float i0 = 0.03125f / ks.x, i1 = 0.03125f / ks.y;
        float i2 = 0.03125f / ks.z, i3 = 0.03125f / ks.w;
        ushort4 o;
        o.x = f2b(e0 * inv * i0); o.y = f2b(e1 * inv * i1);
        o.z = f2b(e2 * inv * i2); o.w = f2b(e3 * inv * i3);
        *(ushort4*)&p[t * 4] = o;
    } else {                                   // vE[b][s][e] -> vET[b][e][s]
        int j = bid - 8192;
        int b = j >> 9, y = (j >> 5) & 15, x = j & 31;
        int s0 = x * 64, e0 = y * 64;
        int lr = t >> 4, lc = (t & 15) * 4;
#pragma unroll
        for (int i = 0; i < 4; ++i) {
            int sr = i * 16 + lr;
            ushort4 v = *(const ushort4*)(vE + ((size_t)b * 2048 + s0 + sr) * 1024 + e0 + lc);
            tile[sr][lc] = v.x; tile[sr][lc + 1] = v.y;
            tile[sr][lc + 2] = v.z; tile[sr][lc + 3] = v.w;
        }
        __syncthreads();
#pragma unroll
        for (int i = 0; i < 4; ++i) {
            int er = i * 16 + lr;
            ushort4 v;
            v.x = tile[lc + 0][er]; v.y = tile[lc + 1][er];
            v.z = tile[lc + 2][er]; v.w = tile[lc + 3][er];
            *(ushort4*)(vET + ((size_t)b * 1024 + e0 + er) * 2048 + s0 + lc) = v;
        }
    }
}

extern "C" void kernel_launch(void* const* d_in, const int* in_sizes, int n_in,
                              void* d_out, int out_size, void* d_ws, size_t ws_size,
                              hipStream_t stream)
{
    const float* q  = (const float*)d_in[0];
    const float* k  = (const float*)d_in[1];
    const float* v  = (const float*)d_in[2];
    const float* Wq = (const float*)d_in[3];
    const float* bq = (const float*)d_in[4];
    const float* Wk = (const float*)d_in[5];
    const float* bk = (const float*)d_in[6];
    const float* Wv = (const float*)d_in[7];
    const float* bv = (const float*)d_in[8];

    float* out  = (float*)d_out;          // [4,2048,1024] fp32
    float* attn = out + 8388608;          // [4,2048,2048] fp32

    u16* wsU = (u16*)d_ws;
    u16* qE   = wsU;                      // R0: exp'd q logits -> qp*kinv
    u16* kE   = wsU + 8388608;            // R1: exp'd k logits (stays raw)
    u16* Wb   = wsU + 16777216;           // R2: Wqb|Wkb|Wvb (stride 1M)
    u16* qb   = wsU + 25165824;           // R3: q bf16 (dead after proj)
    u16* kb   = wsU + 33554432;           // R4: k bf16 (dead after proj)
    u16* vb   = wsU + 41943040;           // R4+8.4M: v bf16 (dead after proj)
    u16* vET  = wsU + 25165824;           // R3 after proj: vET [4,1024,2048]
    u16* attnB = wsU + 33554432;          // R4 after proj: attn bf16
    u16* vE   = (u16*)attn;               // d_out attn region as scratch

    float* tail  = (float*)(wsU + 50331648);
    float* csum  = tail;                  // kcolsum[4][1024] | vcolsum[4][1024]
    float* biasCat = tail + 139264;       // [3,1024] bq|bk|bv

    const long long SD = 2048LL * 1024, SS = 2048LL * 2048, DS = 1024LL * 2048;

    // ---- 1: convert inputs + weights to bf16, gather biases, zero csum ----
    cvt_all<<<dim3(27649), dim3(256), 0, stream>>>(
        (const float4*)q, (const float4*)k, (const float4*)v,
        (const float4*)Wq, (const float4*)Wk, (const float4*)Wv,
        bq, bk, bv,
        (ushort4*)qb, (ushort4*)kb, (ushort4*)vb, (ushort4*)Wb, biasCat, csum);

    // ---- 2: projections (BM=256 ring) + fused k/v colsums ----
    gemm_bw<1, 256><<<dim3(8, 32, 3), dim3(256), 0, stream>>>(
        qb, Wb, nullptr, qE, vE, biasCat, csum,
        1024, 1024, 8388608LL, 1048576LL, 8388608LL);

    // ---- 3: qE row softmax (kinv inline) + vE -> vET transpose ----
    qsm_vtrans<<<dim3(10240), dim3(256), 0, stream>>>(qE, csum, vE, vET);

    // ---- 4: attn = (qp*kinv) @ kE^T -> fp32 d_out + bf16 attnB ----
    gemm256_attn<<<dim3(8, 8, 4), dim3(512), 0, stream>>>(
        qE, kE, attn, attnB, 2048, 1024, SD, SD, SS);

    // ---- 5: out = (attnB @ vET^T) * (1/vsum) -> fp32 d_out ----
    gemm_bw<2, 128><<<dim3(8, 16, 4), dim3(256), 0, stream>>>(
        attnB, vET, out, nullptr, nullptr, nullptr, csum + 4096,
        1024, 2048, SS, DS, SD);
}